// Round 2
// baseline (1272.467 us; speedup 1.0000x reference)
//
#include <hip/hip_runtime.h>
#include <hip/hip_bf16.h>

// GIN: 3x [scatter-sum + MLP(64->64->64) + relu] + mean-pool(128 graphs) + linear(64->10)
// Reference dtypes: float32 tensors, int32 indices, float32 output.
// MFMA fragments cast f32->bf16 at point of use; all storage/accumulation f32.

#define N_NODES 100000
#define N_EDGES 1200000
#define DIM     64
#define N_GRAPH 128
#define N_CLS   10

typedef __bf16 bf16_t;
typedef __bf16 bf16x8 __attribute__((ext_vector_type(8)));
typedef float  f32x4  __attribute__((ext_vector_type(4)));

// ---------------------------------------------------------------------------
// agg[dst][f] += x[src][f] over all edges. One thread per (edge, feature).
// 76.8M HW fp32 atomics; e is wave-uniform (64 lanes = 64 features of 1 edge).
// ---------------------------------------------------------------------------
__global__ void scatter_kernel(const float* __restrict__ x,
                               const int* __restrict__ ei,
                               float* __restrict__ agg) {
    int i = blockIdx.x * 256 + threadIdx.x;   // < E*64 = 76.8M (grid sized exactly)
    int f = i & 63;
    int e = i >> 6;
    int src = ei[e];
    int dst = ei[N_EDGES + e];
    float v = x[src * 64 + f];
    unsafeAtomicAdd(agg + dst * 64 + f, v);   // HW global_atomic_add_f32 (no CAS loop)
}

// ---------------------------------------------------------------------------
// xout = relu( relu((xin+agg) @ wa + ba) @ wb + bb )   (all f32 storage)
// Block = 256 (4 waves). Wave w handles rows [tile*64 + w*16, +16).
// MFMA 16x16x32 bf16 (inputs cast f32->bf16 in-register).
// A-layout: A[m=lane&15][k=quad*8+j]; B: B[k=quad*8+j][n=lane&15];
// C/D: row=quad*4+r, col=lane&15.
// h1 C-layout -> A-layout via per-wave padded LDS tile (stride 72 bf16).
// ---------------------------------------------------------------------------
__global__ void mlp_kernel(const float* __restrict__ xin,
                           const float* __restrict__ agg,
                           const float* __restrict__ wa, const float* __restrict__ ba,
                           const float* __restrict__ wb, const float* __restrict__ bb,
                           float* __restrict__ xout) {
    __shared__ __align__(16) bf16_t h1s[4][16][72];

    const int tid  = threadIdx.x;
    const int wv   = tid >> 6;
    const int lane = tid & 63;
    const int l15  = lane & 15;
    const int quad = lane >> 4;

    // --- load B fragments + biases (once per block; L1/L2 hits) ---
    bf16x8 bfa[4][2], bfb[4][2];
    float  bav[4], bbv[4];
#pragma unroll
    for (int ct = 0; ct < 4; ++ct) {
        const int n = ct * 16 + l15;
#pragma unroll
        for (int ks = 0; ks < 2; ++ks) {
            bf16x8 t1, t2;
#pragma unroll
            for (int j = 0; j < 8; ++j) {
                const int k = ks * 32 + quad * 8 + j;
                t1[j] = (bf16_t)wa[k * 64 + n];
                t2[j] = (bf16_t)wb[k * 64 + n];
            }
            bfa[ct][ks] = t1;
            bfb[ct][ks] = t2;
        }
        bav[ct] = ba[n];
        bbv[ct] = bb[n];
    }

    const int ntiles = (N_NODES + 63) / 64;   // 1563
    for (int tile = blockIdx.x; tile < ntiles; tile += gridDim.x) {
        const int rowa = tile * 64 + wv * 16 + l15;          // A-load row
        const int rowc = rowa < N_NODES ? rowa : N_NODES - 1;

        // A fragments: in[row][k] = bf16( x + agg ), f32 source
        bf16x8 af[2];
#pragma unroll
        for (int ks = 0; ks < 2; ++ks) {
            const int k0 = ks * 32 + quad * 8;
            const f32x4 x0 = *(const f32x4*)(xin + rowc * 64 + k0);
            const f32x4 x1 = *(const f32x4*)(xin + rowc * 64 + k0 + 4);
            const f32x4 a0 = *(const f32x4*)(agg + rowc * 64 + k0);
            const f32x4 a1 = *(const f32x4*)(agg + rowc * 64 + k0 + 4);
            bf16x8 t;
#pragma unroll
            for (int j = 0; j < 4; ++j) t[j]     = (bf16_t)(x0[j] + a0[j]);
#pragma unroll
            for (int j = 0; j < 4; ++j) t[4 + j] = (bf16_t)(x1[j] + a1[j]);
            af[ks] = t;
        }

        // GEMM1 -> h1 (relu) into LDS
#pragma unroll
        for (int ct = 0; ct < 4; ++ct) {
            f32x4 acc = {0.f, 0.f, 0.f, 0.f};
            acc = __builtin_amdgcn_mfma_f32_16x16x32_bf16(af[0], bfa[ct][0], acc, 0, 0, 0);
            acc = __builtin_amdgcn_mfma_f32_16x16x32_bf16(af[1], bfa[ct][1], acc, 0, 0, 0);
#pragma unroll
            for (int r = 0; r < 4; ++r) {
                float h = acc[r] + bav[ct];
                h = h > 0.f ? h : 0.f;
                h1s[wv][quad * 4 + r][ct * 16 + l15] = (bf16_t)h;
            }
        }
        __syncthreads();

        // A2 fragments from LDS (row stride 144B, 16B aligned)
        bf16x8 a2[2];
#pragma unroll
        for (int ks = 0; ks < 2; ++ks)
            a2[ks] = *(const bf16x8*)(&h1s[wv][l15][ks * 32 + quad * 8]);

        // GEMM2 -> relu -> store f32
#pragma unroll
        for (int ct = 0; ct < 4; ++ct) {
            f32x4 acc = {0.f, 0.f, 0.f, 0.f};
            acc = __builtin_amdgcn_mfma_f32_16x16x32_bf16(a2[0], bfb[ct][0], acc, 0, 0, 0);
            acc = __builtin_amdgcn_mfma_f32_16x16x32_bf16(a2[1], bfb[ct][1], acc, 0, 0, 0);
#pragma unroll
            for (int r = 0; r < 4; ++r) {
                const int orow = tile * 64 + wv * 16 + quad * 4 + r;
                if (orow < N_NODES) {
                    float h = acc[r] + bbv[ct];
                    h = h > 0.f ? h : 0.f;
                    xout[orow * 64 + ct * 16 + l15] = h;
                }
            }
        }
        __syncthreads();   // h1s reuse next tile iteration
    }
}

// ---------------------------------------------------------------------------
// Mean-pool numerator: batch is sorted, so each 64-lane group walks a node run
// and emits one atomic per graph transition (~20k atomics total).
// ---------------------------------------------------------------------------
__global__ void pool_kernel(const float* __restrict__ x,
                            const int* __restrict__ batch,
                            float* __restrict__ gsum) {
    const int f  = threadIdx.x & 63;
    const int sg = threadIdx.x >> 6;
    const int n0 = blockIdx.x * 512 + sg * 128;
    const int n1 = (n0 + 128 < N_NODES) ? (n0 + 128) : N_NODES;
    float acc = 0.f;
    int cur = -1;
    for (int n = n0; n < n1; ++n) {
        const int g = batch[n];            // wave-uniform broadcast
        if (g != cur) {
            if (cur >= 0) unsafeAtomicAdd(gsum + cur * 64 + f, acc);
            acc = 0.f;
            cur = g;
        }
        acc += x[n * 64 + f];
    }
    if (cur >= 0) unsafeAtomicAdd(gsum + cur * 64 + f, acc);
}

__global__ void count_kernel(const int* __restrict__ batch, int* __restrict__ gcnt) {
    const int n = blockIdx.x * 256 + threadIdx.x;
    if (n < N_NODES) atomicAdd(gcnt + batch[n], 1);
}

// out[g][c] = (gsum[g]/max(cnt,1)) . wc[:,c] + bc[c]
__global__ void cls_kernel(const float* __restrict__ gsum, const int* __restrict__ gcnt,
                           const float* __restrict__ wc, const float* __restrict__ bc,
                           float* __restrict__ out) {
    const int g = blockIdx.x;
    const int c = threadIdx.x;
    if (c >= N_CLS) return;
    float cnt = (float)gcnt[g];
    cnt = cnt > 1.f ? cnt : 1.f;
    const float inv = 1.f / cnt;
    float acc = bc[c];
    for (int k = 0; k < 64; ++k)
        acc += gsum[g * 64 + k] * inv * wc[k * N_CLS + c];
    out[g * N_CLS + c] = acc;
}

// ---------------------------------------------------------------------------
extern "C" void kernel_launch(void* const* d_in, const int* in_sizes, int n_in,
                              void* d_out, int out_size, void* d_ws, size_t ws_size,
                              hipStream_t stream) {
    const float* x   = (const float*)d_in[0];
    const float* w1a = (const float*)d_in[1];
    const float* b1a = (const float*)d_in[2];
    const float* w1b = (const float*)d_in[3];
    const float* b1b = (const float*)d_in[4];
    const float* w2a = (const float*)d_in[5];
    const float* b2a = (const float*)d_in[6];
    const float* w2b = (const float*)d_in[7];
    const float* b2b = (const float*)d_in[8];
    const float* w3a = (const float*)d_in[9];
    const float* b3a = (const float*)d_in[10];
    const float* w3b = (const float*)d_in[11];
    const float* b3b = (const float*)d_in[12];
    const float* wc  = (const float*)d_in[13];
    const float* bc  = (const float*)d_in[14];
    const int*   ei    = (const int*)d_in[15];
    const int*   batch = (const int*)d_in[16];
    float* out = (float*)d_out;

    // workspace layout (76.8 MB + pool buffers, 16B-aligned offsets)
    char*  ws   = (char*)d_ws;
    float* agg  = (float*)ws;                       // N*64 f32 = 25,600,000 B
    float* xA   = (float*)(ws + 25600000);          // N*64 f32 = 25,600,000 B
    float* xB   = (float*)(ws + 51200000);          // N*64 f32 = 25,600,000 B
    float* gsum = (float*)(ws + 76800000);          // G*64 f32 = 32,768 B
    int*   gcnt = (int*)(ws + 76832768);            // G int    = 512 B

    const int scat_grid = (N_EDGES * 64) / 256;     // 300000 (exact)
    const int mlp_grid  = 512;                      // grid-stride over 1563 tiles
    const size_t agg_bytes = (size_t)N_NODES * 64 * sizeof(float);

    // layer 1
    hipMemsetAsync(agg, 0, agg_bytes, stream);
    scatter_kernel<<<scat_grid, 256, 0, stream>>>(x, ei, agg);
    mlp_kernel<<<mlp_grid, 256, 0, stream>>>(x, agg, w1a, b1a, w1b, b1b, xA);
    // layer 2
    hipMemsetAsync(agg, 0, agg_bytes, stream);
    scatter_kernel<<<scat_grid, 256, 0, stream>>>(xA, ei, agg);
    mlp_kernel<<<mlp_grid, 256, 0, stream>>>(xA, agg, w2a, b2a, w2b, b2b, xB);
    // layer 3
    hipMemsetAsync(agg, 0, agg_bytes, stream);
    scatter_kernel<<<scat_grid, 256, 0, stream>>>(xB, ei, agg);
    mlp_kernel<<<mlp_grid, 256, 0, stream>>>(xB, agg, w3a, b3a, w3b, b3b, xA);
    // pool + classify
    hipMemsetAsync(gsum, 0, 32768 + 512, stream);   // gsum + gcnt contiguous
    count_kernel<<<(N_NODES + 255) / 256, 256, 0, stream>>>(batch, gcnt);
    pool_kernel<<<(N_NODES + 511) / 512, 256, 0, stream>>>(xA, batch, gsum);
    cls_kernel<<<N_GRAPH, 64, 0, stream>>>(gsum, gcnt, wc, bc, out);
}

// Round 3
// 794.401 us; speedup vs baseline: 1.6018x; 1.6018x over previous
//
#include <hip/hip_runtime.h>
#include <hip/hip_bf16.h>

// GIN: 3x [CSR gather-sum + MLP(64->64->64) + relu] + mean-pool(128) + linear(64->10)
// f32 storage throughout; MFMA operands cast f32->bf16 in-register.
// CSR (edges sorted by dst) built once per launch, reused for all 3 layers.

#define N_NODES 100000
#define N_EDGES 1200000
#define DIM     64
#define N_GRAPH 128
#define N_CLS   10

typedef __bf16 bf16_t;
typedef __bf16 bf16x8 __attribute__((ext_vector_type(8)));
typedef float  f32x4  __attribute__((ext_vector_type(4)));

// ---------------------------------------------------------------------------
// CSR build step 1: degree histogram into cur[] (zeroed by memset).
// 1.2M int atomics over 100k counters — low contention.
// ---------------------------------------------------------------------------
__global__ void deg_kernel(const int* __restrict__ ei, int* __restrict__ cur) {
    const int e = blockIdx.x * 256 + threadIdx.x;
    if (e < N_EDGES) atomicAdd(cur + ei[N_EDGES + e], 1);
}

// ---------------------------------------------------------------------------
// CSR build step 2: single-block exclusive scan of cur (degrees).
// Writes offset[0..N] and rewrites cur[] as the fill cursor (== offset copy).
// ---------------------------------------------------------------------------
__global__ void scan_kernel(int* __restrict__ cur, int* __restrict__ offset) {
    __shared__ int a[1024];
    const int t = threadIdx.x;
    const int chunk = (N_NODES + 1023) / 1024;          // 98
    const int lo = t * chunk;
    const int hi = (lo + chunk < N_NODES) ? lo + chunk : N_NODES;

    int s = 0;
    for (int p = lo; p < hi; ++p) s += cur[p];
    a[t] = s;
    __syncthreads();
    for (int d = 1; d < 1024; d <<= 1) {                // inclusive block scan
        int v = a[t];
        if (t >= d) v += a[t - d];
        __syncthreads();
        a[t] = v;
        __syncthreads();
    }
    int run = (t == 0) ? 0 : a[t - 1];                  // exclusive base
    for (int p = lo; p < hi; ++p) {
        const int d = cur[p];
        offset[p] = run;
        cur[p] = run;                                   // fill cursor
        run += d;
    }
    if (lo < N_NODES && hi == N_NODES) offset[N_NODES] = run;   // == E
}

// ---------------------------------------------------------------------------
// CSR build step 3: scatter src indices into dst-sorted adjacency.
// ---------------------------------------------------------------------------
__global__ void fill_kernel(const int* __restrict__ ei, int* __restrict__ cur,
                            int* __restrict__ csr) {
    const int e = blockIdx.x * 256 + threadIdx.x;
    if (e < N_EDGES) {
        const int pos = atomicAdd(cur + ei[N_EDGES + e], 1);
        csr[pos] = ei[e];
    }
}

// ---------------------------------------------------------------------------
// hout[n] = x[n] + sum_{s in N(n)} x[s].  One wave per node, lane = feature.
// Neighbor row reads are 256B coalesced (mostly L2/LLC hits); no atomics.
// ---------------------------------------------------------------------------
__global__ void agg_kernel(const float* __restrict__ x,
                           const int* __restrict__ offset,
                           const int* __restrict__ csr,
                           float* __restrict__ hout) {
    const int node = (blockIdx.x * 256 + threadIdx.x) >> 6;   // grid sized exactly
    const int f = threadIdx.x & 63;
    const int o0 = offset[node];
    const int o1 = offset[node + 1];

    float acc = x[node * 64 + f];
    for (int i = o0; i < o1; i += 64) {
        const int cnt = (o1 - i < 64) ? (o1 - i) : 64;
        int s = 0;
        if (i + f < o1) s = csr[i + f];
        for (int j = 0; j < cnt; ++j) {
            const int sj = __shfl(s, j);                      // uniform broadcast
            acc += x[sj * 64 + f];
        }
    }
    hout[node * 64 + f] = acc;
}

// ---------------------------------------------------------------------------
// xout = relu( relu(hin @ wa + ba) @ wb + bb )   (f32 storage)
// Block = 256 (4 waves). Wave w: rows [tile*64 + w*16, +16). MFMA 16x16x32 bf16.
// A: A[m=lane&15][k=quad*8+j]; B: B[k=quad*8+j][n=lane&15]; C/D: row=quad*4+r, col=lane&15.
// h1 C-layout -> A-layout via per-wave padded LDS tile (stride 72 bf16).
// ---------------------------------------------------------------------------
__global__ void mlp_kernel(const float* __restrict__ hin,
                           const float* __restrict__ wa, const float* __restrict__ ba,
                           const float* __restrict__ wb, const float* __restrict__ bb,
                           float* __restrict__ xout) {
    __shared__ __align__(16) bf16_t h1s[4][16][72];

    const int tid  = threadIdx.x;
    const int wv   = tid >> 6;
    const int lane = tid & 63;
    const int l15  = lane & 15;
    const int quad = lane >> 4;

    // B fragments + biases (once per block)
    bf16x8 bfa[4][2], bfb[4][2];
    float  bav[4], bbv[4];
#pragma unroll
    for (int ct = 0; ct < 4; ++ct) {
        const int n = ct * 16 + l15;
#pragma unroll
        for (int ks = 0; ks < 2; ++ks) {
            bf16x8 t1, t2;
#pragma unroll
            for (int j = 0; j < 8; ++j) {
                const int k = ks * 32 + quad * 8 + j;
                t1[j] = (bf16_t)wa[k * 64 + n];
                t2[j] = (bf16_t)wb[k * 64 + n];
            }
            bfa[ct][ks] = t1;
            bfb[ct][ks] = t2;
        }
        bav[ct] = ba[n];
        bbv[ct] = bb[n];
    }

    const int ntiles = (N_NODES + 63) / 64;   // 1563
    for (int tile = blockIdx.x; tile < ntiles; tile += gridDim.x) {
        const int rowa = tile * 64 + wv * 16 + l15;
        const int rowc = rowa < N_NODES ? rowa : N_NODES - 1;

        bf16x8 af[2];
#pragma unroll
        for (int ks = 0; ks < 2; ++ks) {
            const int k0 = ks * 32 + quad * 8;
            const f32x4 x0 = *(const f32x4*)(hin + rowc * 64 + k0);
            const f32x4 x1 = *(const f32x4*)(hin + rowc * 64 + k0 + 4);
            bf16x8 t;
#pragma unroll
            for (int j = 0; j < 4; ++j) t[j]     = (bf16_t)x0[j];
#pragma unroll
            for (int j = 0; j < 4; ++j) t[4 + j] = (bf16_t)x1[j];
            af[ks] = t;
        }

        // GEMM1 -> relu -> LDS
#pragma unroll
        for (int ct = 0; ct < 4; ++ct) {
            f32x4 acc = {0.f, 0.f, 0.f, 0.f};
            acc = __builtin_amdgcn_mfma_f32_16x16x32_bf16(af[0], bfa[ct][0], acc, 0, 0, 0);
            acc = __builtin_amdgcn_mfma_f32_16x16x32_bf16(af[1], bfa[ct][1], acc, 0, 0, 0);
#pragma unroll
            for (int r = 0; r < 4; ++r) {
                float h = acc[r] + bav[ct];
                h = h > 0.f ? h : 0.f;
                h1s[wv][quad * 4 + r][ct * 16 + l15] = (bf16_t)h;
            }
        }
        __syncthreads();

        bf16x8 a2[2];
#pragma unroll
        for (int ks = 0; ks < 2; ++ks)
            a2[ks] = *(const bf16x8*)(&h1s[wv][l15][ks * 32 + quad * 8]);

        // GEMM2 -> relu -> store
#pragma unroll
        for (int ct = 0; ct < 4; ++ct) {
            f32x4 acc = {0.f, 0.f, 0.f, 0.f};
            acc = __builtin_amdgcn_mfma_f32_16x16x32_bf16(a2[0], bfb[ct][0], acc, 0, 0, 0);
            acc = __builtin_amdgcn_mfma_f32_16x16x32_bf16(a2[1], bfb[ct][1], acc, 0, 0, 0);
#pragma unroll
            for (int r = 0; r < 4; ++r) {
                const int orow = tile * 64 + wv * 16 + quad * 4 + r;
                if (orow < N_NODES) {
                    float h = acc[r] + bbv[ct];
                    h = h > 0.f ? h : 0.f;
                    xout[orow * 64 + ct * 16 + l15] = h;
                }
            }
        }
        __syncthreads();
    }
}

// ---------------------------------------------------------------------------
// Mean-pool numerator: batch sorted -> one atomic per graph transition per wave.
// ---------------------------------------------------------------------------
__global__ void pool_kernel(const float* __restrict__ x,
                            const int* __restrict__ batch,
                            float* __restrict__ gsum) {
    const int f  = threadIdx.x & 63;
    const int sg = threadIdx.x >> 6;
    const int n0 = blockIdx.x * 512 + sg * 128;
    const int n1 = (n0 + 128 < N_NODES) ? (n0 + 128) : N_NODES;
    float acc = 0.f;
    int cur = -1;
    for (int n = n0; n < n1; ++n) {
        const int g = batch[n];
        if (g != cur) {
            if (cur >= 0) unsafeAtomicAdd(gsum + cur * 64 + f, acc);
            acc = 0.f;
            cur = g;
        }
        acc += x[n * 64 + f];
    }
    if (cur >= 0) unsafeAtomicAdd(gsum + cur * 64 + f, acc);
}

// out[g][c] = (gsum[g]/max(cnt,1)) . wc[:,c] + bc[c]; cnt via binary search (batch sorted)
__global__ void cls_kernel(const float* __restrict__ gsum,
                           const int* __restrict__ batch,
                           const float* __restrict__ wc, const float* __restrict__ bc,
                           float* __restrict__ out) {
    const int g = blockIdx.x;
    const int c = threadIdx.x;
    if (c >= N_CLS) return;
    int lo = 0, hi = N_NODES;
    while (lo < hi) { const int m = (lo + hi) >> 1; if (batch[m] < g) lo = m + 1; else hi = m; }
    const int lb = lo;
    lo = 0; hi = N_NODES;
    while (lo < hi) { const int m = (lo + hi) >> 1; if (batch[m] <= g) lo = m + 1; else hi = m; }
    const int cnt = lo - lb;
    const float inv = 1.f / (float)(cnt > 1 ? cnt : 1);
    float acc = bc[c];
    for (int k = 0; k < 64; ++k)
        acc += gsum[g * 64 + k] * inv * wc[k * N_CLS + c];
    out[g * N_CLS + c] = acc;
}

// ---------------------------------------------------------------------------
extern "C" void kernel_launch(void* const* d_in, const int* in_sizes, int n_in,
                              void* d_out, int out_size, void* d_ws, size_t ws_size,
                              hipStream_t stream) {
    const float* x   = (const float*)d_in[0];
    const float* w1a = (const float*)d_in[1];
    const float* b1a = (const float*)d_in[2];
    const float* w1b = (const float*)d_in[3];
    const float* b1b = (const float*)d_in[4];
    const float* w2a = (const float*)d_in[5];
    const float* b2a = (const float*)d_in[6];
    const float* w2b = (const float*)d_in[7];
    const float* b2b = (const float*)d_in[8];
    const float* w3a = (const float*)d_in[9];
    const float* b3a = (const float*)d_in[10];
    const float* w3b = (const float*)d_in[11];
    const float* b3b = (const float*)d_in[12];
    const float* wc  = (const float*)d_in[13];
    const float* bc  = (const float*)d_in[14];
    const int*   ei    = (const int*)d_in[15];
    const int*   batch = (const int*)d_in[16];
    float* out = (float*)d_out;

    // workspace layout (~56.9 MB, 16B-aligned)
    char*  ws     = (char*)d_ws;
    int*   cur    = (int*)ws;                      // N ints        = 400,000 B
    int*   offset = (int*)(ws + 400000);           // N+1 ints      = 400,004 B
    int*   csr    = (int*)(ws + 800016);           // E ints        = 4,800,000 B
    float* h      = (float*)(ws + 5600016);        // N*64 f32      = 25,600,000 B
    float* xA     = (float*)(ws + 31200016);       // N*64 f32      = 25,600,000 B
    float* gsum   = (float*)(ws + 56800016);       // G*64 f32      = 32,768 B

    const int egrid   = (N_EDGES + 255) / 256;     // 4688
    const int agrid   = (N_NODES * 64) / 256;      // 25000 (exact)
    const int mlpgrid = 512;

    // CSR build (once, reused 3x)
    hipMemsetAsync(cur, 0, (size_t)N_NODES * sizeof(int), stream);
    deg_kernel<<<egrid, 256, 0, stream>>>(ei, cur);
    scan_kernel<<<1, 1024, 0, stream>>>(cur, offset);
    fill_kernel<<<egrid, 256, 0, stream>>>(ei, cur, csr);

    // layer 1
    agg_kernel<<<agrid, 256, 0, stream>>>(x, offset, csr, h);
    mlp_kernel<<<mlpgrid, 256, 0, stream>>>(h, w1a, b1a, w1b, b1b, xA);
    // layer 2
    agg_kernel<<<agrid, 256, 0, stream>>>(xA, offset, csr, h);
    mlp_kernel<<<mlpgrid, 256, 0, stream>>>(h, w2a, b2a, w2b, b2b, xA);
    // layer 3
    agg_kernel<<<agrid, 256, 0, stream>>>(xA, offset, csr, h);
    mlp_kernel<<<mlpgrid, 256, 0, stream>>>(h, w3a, b3a, w3b, b3b, xA);

    // pool + classify
    hipMemsetAsync(gsum, 0, 32768, stream);
    pool_kernel<<<(N_NODES + 511) / 512, 256, 0, stream>>>(xA, batch, gsum);
    cls_kernel<<<N_GRAPH, 64, 0, stream>>>(gsum, batch, wc, bc, out);
}

// Round 4
// 568.398 us; speedup vs baseline: 2.2387x; 1.3976x over previous
//
#include <hip/hip_runtime.h>
#include <hip/hip_bf16.h>

// GIN: 3x [CSR gather-sum + MLP(64->64->64) + relu] + mean-pool(128) + linear(64->10)
// Inputs f32; intermediates bf16 (h is bf16-identical to the MFMA cast path);
// accumulation f32. CSR built per launch (parallel scan), reused for 3 layers.

#define N_NODES 100000
#define N_EDGES 1200000
#define N_GRAPH 128
#define N_CLS   10
#define NBLK    391        // ceil(N_NODES/256)

typedef __bf16 bf16_t;
typedef __bf16 bf16x8 __attribute__((ext_vector_type(8)));
typedef float  f32x4  __attribute__((ext_vector_type(4)));

// ---------------- CSR build ----------------
__global__ void deg_kernel(const int* __restrict__ ei, int* __restrict__ cur) {
    const int e = (blockIdx.x * 256 + threadIdx.x) * 4;
    if (e >= N_EDGES) return;
    const int4 d = *(const int4*)(ei + N_EDGES + e);
    atomicAdd(cur + d.x, 1);
    atomicAdd(cur + d.y, 1);
    atomicAdd(cur + d.z, 1);
    atomicAdd(cur + d.w, 1);
}

// stage 1: per-block (256-elem) sums
__global__ void scan1_kernel(const int* __restrict__ cur, int* __restrict__ bsum) {
    __shared__ int l[256];
    const int t = threadIdx.x;
    const int idx = blockIdx.x * 256 + t;
    l[t] = (idx < N_NODES) ? cur[idx] : 0;
    __syncthreads();
    for (int d = 128; d > 0; d >>= 1) {
        if (t < d) l[t] += l[t + d];
        __syncthreads();
    }
    if (t == 0) bsum[blockIdx.x] = l[0];
}

// stage 2: exclusive scan of 391 block sums (single block)
__global__ void scan2_kernel(const int* __restrict__ bsum, int* __restrict__ bbase,
                             int* __restrict__ offset) {
    __shared__ int l[512];
    const int t = threadIdx.x;
    const int v = (t < NBLK) ? bsum[t] : 0;
    l[t] = v;
    __syncthreads();
    for (int d = 1; d < 512; d <<= 1) {
        int u = l[t];
        if (t >= d) u += l[t - d];
        __syncthreads();
        l[t] = u;
        __syncthreads();
    }
    if (t < NBLK) bbase[t] = l[t] - v;
    if (t == 0) offset[N_NODES] = N_EDGES;   // total is a constant
}

// stage 3: block-local exclusive scan + global base -> offset[], cur[] (fill cursor)
__global__ void scan3_kernel(int* __restrict__ cur, const int* __restrict__ bbase,
                             int* __restrict__ offset) {
    __shared__ int l[256];
    const int t = threadIdx.x;
    const int idx = blockIdx.x * 256 + t;
    const int v = (idx < N_NODES) ? cur[idx] : 0;
    l[t] = v;
    __syncthreads();
    for (int d = 1; d < 256; d <<= 1) {
        int u = l[t];
        if (t >= d) u += l[t - d];
        __syncthreads();
        l[t] = u;
        __syncthreads();
    }
    if (idx < N_NODES) {
        const int excl = bbase[blockIdx.x] + l[t] - v;
        offset[idx] = excl;
        cur[idx] = excl;
    }
}

__global__ void fill_kernel(const int* __restrict__ ei, int* __restrict__ cur,
                            int* __restrict__ csr) {
    const int e = (blockIdx.x * 256 + threadIdx.x) * 4;
    if (e >= N_EDGES) return;
    const int4 s = *(const int4*)(ei + e);
    const int4 d = *(const int4*)(ei + N_EDGES + e);
    int p;
    p = atomicAdd(cur + d.x, 1); csr[p] = s.x;
    p = atomicAdd(cur + d.y, 1); csr[p] = s.y;
    p = atomicAdd(cur + d.z, 1); csr[p] = s.z;
    p = atomicAdd(cur + d.w, 1); csr[p] = s.w;
}

// ---------------------------------------------------------------------------
// hout[n] = bf16( x[n] + sum_{s in N(n)} x[s] ).  One wave per node, lane=feature.
// T = float (layer 1 input) or bf16 (layer 2/3). f32 accumulation.
// ---------------------------------------------------------------------------
template <typename T>
__global__ void agg_kernel(const T* __restrict__ x,
                           const int* __restrict__ offset,
                           const int* __restrict__ csr,
                           bf16_t* __restrict__ hout) {
    const int node = (blockIdx.x * 256 + threadIdx.x) >> 6;   // grid sized exactly
    const int f = threadIdx.x & 63;
    const int o0 = offset[node];
    const int o1 = offset[node + 1];

    float acc = (float)x[node * 64 + f];
    for (int i = o0; i < o1; i += 64) {
        const int cnt = (o1 - i < 64) ? (o1 - i) : 64;
        int s = 0;
        if (i + f < o1) s = csr[i + f];
        for (int j = 0; j < cnt; ++j) {
            const int sj = __shfl(s, j);                      // uniform broadcast
            acc += (float)x[sj * 64 + f];
        }
    }
    hout[node * 64 + f] = (bf16_t)acc;
}

// ---------------------------------------------------------------------------
// xout = bf16( relu( relu(hin @ wa + ba) @ wb + bb ) )
// Block=256 (4 waves), wave w: rows [tile*64+w*16, +16). MFMA 16x16x32 bf16.
// A: A[m=lane&15][k=quad*8+j]; B: B[k=quad*8+j][n=lane&15]; C/D: row=quad*4+r, col=lane&15.
// h1 C-layout -> A-layout via per-wave padded LDS tile (stride 72 bf16).
// ---------------------------------------------------------------------------
__global__ void mlp_kernel(const bf16_t* __restrict__ hin,
                           const float* __restrict__ wa, const float* __restrict__ ba,
                           const float* __restrict__ wb, const float* __restrict__ bb,
                           bf16_t* __restrict__ xout) {
    __shared__ __align__(16) bf16_t h1s[4][16][72];

    const int tid  = threadIdx.x;
    const int wv   = tid >> 6;
    const int lane = tid & 63;
    const int l15  = lane & 15;
    const int quad = lane >> 4;

    // B fragments + biases (once per block)
    bf16x8 bfa[4][2], bfb[4][2];
    float  bav[4], bbv[4];
#pragma unroll
    for (int ct = 0; ct < 4; ++ct) {
        const int n = ct * 16 + l15;
#pragma unroll
        for (int ks = 0; ks < 2; ++ks) {
            bf16x8 t1, t2;
#pragma unroll
            for (int j = 0; j < 8; ++j) {
                const int k = ks * 32 + quad * 8 + j;
                t1[j] = (bf16_t)wa[k * 64 + n];
                t2[j] = (bf16_t)wb[k * 64 + n];
            }
            bfa[ct][ks] = t1;
            bfb[ct][ks] = t2;
        }
        bav[ct] = ba[n];
        bbv[ct] = bb[n];
    }

    const int ntiles = (N_NODES + 63) / 64;   // 1563
    for (int tile = blockIdx.x; tile < ntiles; tile += gridDim.x) {
        const int rowa = tile * 64 + wv * 16 + l15;
        const int rowc = rowa < N_NODES ? rowa : N_NODES - 1;

        // A fragments: direct 16B bf16 loads
        bf16x8 af[2];
#pragma unroll
        for (int ks = 0; ks < 2; ++ks)
            af[ks] = *(const bf16x8*)(hin + rowc * 64 + ks * 32 + quad * 8);

        // GEMM1 -> relu -> LDS
#pragma unroll
        for (int ct = 0; ct < 4; ++ct) {
            f32x4 acc = {0.f, 0.f, 0.f, 0.f};
            acc = __builtin_amdgcn_mfma_f32_16x16x32_bf16(af[0], bfa[ct][0], acc, 0, 0, 0);
            acc = __builtin_amdgcn_mfma_f32_16x16x32_bf16(af[1], bfa[ct][1], acc, 0, 0, 0);
#pragma unroll
            for (int r = 0; r < 4; ++r) {
                float h = acc[r] + bav[ct];
                h = h > 0.f ? h : 0.f;
                h1s[wv][quad * 4 + r][ct * 16 + l15] = (bf16_t)h;
            }
        }
        __syncthreads();

        bf16x8 a2[2];
#pragma unroll
        for (int ks = 0; ks < 2; ++ks)
            a2[ks] = *(const bf16x8*)(&h1s[wv][l15][ks * 32 + quad * 8]);

        // GEMM2 -> relu -> store bf16
#pragma unroll
        for (int ct = 0; ct < 4; ++ct) {
            f32x4 acc = {0.f, 0.f, 0.f, 0.f};
            acc = __builtin_amdgcn_mfma_f32_16x16x32_bf16(a2[0], bfb[ct][0], acc, 0, 0, 0);
            acc = __builtin_amdgcn_mfma_f32_16x16x32_bf16(a2[1], bfb[ct][1], acc, 0, 0, 0);
#pragma unroll
            for (int r = 0; r < 4; ++r) {
                const int orow = tile * 64 + wv * 16 + quad * 4 + r;
                if (orow < N_NODES) {
                    float h = acc[r] + bbv[ct];
                    h = h > 0.f ? h : 0.f;
                    xout[orow * 64 + ct * 16 + l15] = (bf16_t)h;
                }
            }
        }
        __syncthreads();
    }
}

// ---------------------------------------------------------------------------
// Mean-pool numerator: batch sorted -> one atomic per graph transition per wave.
// ---------------------------------------------------------------------------
__global__ void pool_kernel(const bf16_t* __restrict__ x,
                            const int* __restrict__ batch,
                            float* __restrict__ gsum) {
    const int f  = threadIdx.x & 63;
    const int sg = threadIdx.x >> 6;
    const int n0 = blockIdx.x * 512 + sg * 128;
    const int n1 = (n0 + 128 < N_NODES) ? (n0 + 128) : N_NODES;
    float acc = 0.f;
    int cur = -1;
    for (int n = n0; n < n1; ++n) {
        const int g = batch[n];
        if (g != cur) {
            if (cur >= 0) unsafeAtomicAdd(gsum + cur * 64 + f, acc);
            acc = 0.f;
            cur = g;
        }
        acc += (float)x[n * 64 + f];
    }
    if (cur >= 0) unsafeAtomicAdd(gsum + cur * 64 + f, acc);
}

// out[g][c] = (gsum[g]/max(cnt,1)) . wc[:,c] + bc[c]; cnt via binary search (batch sorted)
__global__ void cls_kernel(const float* __restrict__ gsum,
                           const int* __restrict__ batch,
                           const float* __restrict__ wc, const float* __restrict__ bc,
                           float* __restrict__ out) {
    const int g = blockIdx.x;
    const int c = threadIdx.x;
    if (c >= N_CLS) return;
    int lo = 0, hi = N_NODES;
    while (lo < hi) { const int m = (lo + hi) >> 1; if (batch[m] < g) lo = m + 1; else hi = m; }
    const int lb = lo;
    lo = 0; hi = N_NODES;
    while (lo < hi) { const int m = (lo + hi) >> 1; if (batch[m] <= g) lo = m + 1; else hi = m; }
    const int cnt = lo - lb;
    const float inv = 1.f / (float)(cnt > 1 ? cnt : 1);
    float acc = bc[c];
    for (int k = 0; k < 64; ++k)
        acc += gsum[g * 64 + k] * inv * wc[k * N_CLS + c];
    out[g * N_CLS + c] = acc;
}

// ---------------------------------------------------------------------------
extern "C" void kernel_launch(void* const* d_in, const int* in_sizes, int n_in,
                              void* d_out, int out_size, void* d_ws, size_t ws_size,
                              hipStream_t stream) {
    const float* x   = (const float*)d_in[0];
    const float* w1a = (const float*)d_in[1];
    const float* b1a = (const float*)d_in[2];
    const float* w1b = (const float*)d_in[3];
    const float* b1b = (const float*)d_in[4];
    const float* w2a = (const float*)d_in[5];
    const float* b2a = (const float*)d_in[6];
    const float* w2b = (const float*)d_in[7];
    const float* b2b = (const float*)d_in[8];
    const float* w3a = (const float*)d_in[9];
    const float* b3a = (const float*)d_in[10];
    const float* w3b = (const float*)d_in[11];
    const float* b3b = (const float*)d_in[12];
    const float* wc  = (const float*)d_in[13];
    const float* bc  = (const float*)d_in[14];
    const int*   ei    = (const int*)d_in[15];
    const int*   batch = (const int*)d_in[16];
    float* out = (float*)d_out;

    // workspace layout (~31.3 MB, 16B-aligned)
    char*   ws     = (char*)d_ws;
    int*    cur    = (int*)ws;                      // N ints       = 400,000 B
    int*    offset = (int*)(ws + 400000);           // N+1 ints     = 400,004 B
    int*    csr    = (int*)(ws + 800016);           // E ints       = 4,800,000 B
    bf16_t* h      = (bf16_t*)(ws + 5600016);       // N*64 bf16    = 12,800,000 B
    bf16_t* xA     = (bf16_t*)(ws + 18400016);      // N*64 bf16    = 12,800,000 B
    int*    bsum   = (int*)(ws + 31200016);         // NBLK ints
    int*    bbase  = (int*)(ws + 31202000);         // NBLK ints
    float*  gsum   = (float*)(ws + 31204000);       // G*64 f32     = 32,768 B

    const int e4grid  = (N_EDGES / 4 + 255) / 256;  // 1172
    const int agrid   = (N_NODES * 64) / 256;       // 25000 (exact)
    const int mlpgrid = 512;

    // CSR build (once, reused 3x)
    hipMemsetAsync(cur, 0, (size_t)N_NODES * sizeof(int), stream);
    deg_kernel<<<e4grid, 256, 0, stream>>>(ei, cur);
    scan1_kernel<<<NBLK, 256, 0, stream>>>(cur, bsum);
    scan2_kernel<<<1, 512, 0, stream>>>(bsum, bbase, offset);
    scan3_kernel<<<NBLK, 256, 0, stream>>>(cur, bbase, offset);
    fill_kernel<<<e4grid, 256, 0, stream>>>(ei, cur, csr);

    // layer 1 (f32 input)
    agg_kernel<float><<<agrid, 256, 0, stream>>>(x, offset, csr, h);
    mlp_kernel<<<mlpgrid, 256, 0, stream>>>(h, w1a, b1a, w1b, b1b, xA);
    // layer 2
    agg_kernel<bf16_t><<<agrid, 256, 0, stream>>>(xA, offset, csr, h);
    mlp_kernel<<<mlpgrid, 256, 0, stream>>>(h, w2a, b2a, w2b, b2b, xA);
    // layer 3
    agg_kernel<bf16_t><<<agrid, 256, 0, stream>>>(xA, offset, csr, h);
    mlp_kernel<<<mlpgrid, 256, 0, stream>>>(h, w3a, b3a, w3b, b3b, xA);

    // pool + classify
    hipMemsetAsync(gsum, 0, 32768, stream);
    pool_kernel<<<(N_NODES + 511) / 512, 256, 0, stream>>>(xA, batch, gsum);
    cls_kernel<<<N_GRAPH, 64, 0, stream>>>(gsum, batch, wc, bc, out);
}

// Round 5
// 558.892 us; speedup vs baseline: 2.2768x; 1.0170x over previous
//
#include <hip/hip_runtime.h>
#include <hip/hip_bf16.h>

// GIN: 3x [CSR gather-sum + MLP(64->64->64) + relu] + mean-pool(128) + linear(64->10)
// x converted to bf16 once; all agg gathers bf16, f32 accumulate.
// CSR built per launch via 49-bucket radix binning (write-locality), reused 3x.

#define N_NODES 100000
#define N_EDGES 1200000
#define N_GRAPH 128
#define N_CLS   10
#define NBLK    391        // ceil(N_NODES/256)
#define NBUCK   49         // dst >> 11  (100000 < 49*2048)
#define BCAP    32768      // per-bucket pair capacity (expected ~24.6k, +52 sigma)
#define BSH     15         // log2(BCAP)

typedef __bf16 bf16_t;
typedef __bf16 bf16x8 __attribute__((ext_vector_type(8)));
typedef float  f32x4  __attribute__((ext_vector_type(4)));

// ---------------- x -> bf16 ----------------
__global__ void tobf_kernel(const float* __restrict__ x, bf16_t* __restrict__ xb) {
    const int i = (blockIdx.x * 256 + threadIdx.x) * 8;   // 6.4M elems, exact grid
    const f32x4 a = *(const f32x4*)(x + i);
    const f32x4 b = *(const f32x4*)(x + i + 4);
    bf16x8 o;
#pragma unroll
    for (int j = 0; j < 4; ++j) { o[j] = (bf16_t)a[j]; o[4 + j] = (bf16_t)b[j]; }
    *(bf16x8*)(xb + i) = o;
}

// ---------------- CSR build: bucket binning ----------------
// Bin (src,dst) pairs by dst>>11. Per-workgroup LDS histogram -> one global
// cursor reservation per touched bucket -> contiguous writes per run.
__global__ void binA_kernel(const int* __restrict__ ei,
                            int* __restrict__ bcnt,
                            int* __restrict__ bsrc, int* __restrict__ bdst) {
    __shared__ int lcnt[NBUCK];
    __shared__ int lbase[NBUCK];
    const int t = threadIdx.x;
    if (t < NBUCK) lcnt[t] = 0;
    __syncthreads();
    const int e0 = (blockIdx.x * 256 + t) * 4;
    int4 s4, d4; int b[4], r[4];
    const bool valid = e0 < N_EDGES;                      // N_EDGES % 4 == 0
    if (valid) {
        s4 = *(const int4*)(ei + e0);
        d4 = *(const int4*)(ei + N_EDGES + e0);
        b[0] = d4.x >> 11; b[1] = d4.y >> 11; b[2] = d4.z >> 11; b[3] = d4.w >> 11;
        r[0] = atomicAdd(&lcnt[b[0]], 1);
        r[1] = atomicAdd(&lcnt[b[1]], 1);
        r[2] = atomicAdd(&lcnt[b[2]], 1);
        r[3] = atomicAdd(&lcnt[b[3]], 1);
    }
    __syncthreads();
    if (t < NBUCK) {
        const int c = lcnt[t];
        lbase[t] = c ? atomicAdd(&bcnt[t], c) : 0;
    }
    __syncthreads();
    if (valid) {
        const int ss[4] = {s4.x, s4.y, s4.z, s4.w};
        const int dd[4] = {d4.x, d4.y, d4.z, d4.w};
#pragma unroll
        for (int j = 0; j < 4; ++j) {
            const int slot = lbase[b[j]] + r[j];
            if (slot < BCAP) {                            // overflow guard
                bsrc[(b[j] << BSH) + slot] = ss[j];
                bdst[(b[j] << BSH) + slot] = dd[j];
            }
        }
    }
}

// degree count from binned dsts: atomics confined to an 8KB cur-window per bucket
__global__ void deg2_kernel(const int* __restrict__ bdst, const int* __restrict__ bcnt,
                            int* __restrict__ cur) {
    const int i = blockIdx.x * 256 + threadIdx.x;
    const int bucket = i >> BSH;
    const int slot = i & (BCAP - 1);
    if (slot < bcnt[bucket])
        atomicAdd(cur + bdst[i], 1);
}

// stage 1: per-block (256-node) degree sums
__global__ void scan1_kernel(const int* __restrict__ cur, int* __restrict__ bsum) {
    __shared__ int l[256];
    const int t = threadIdx.x;
    const int idx = blockIdx.x * 256 + t;
    l[t] = (idx < N_NODES) ? cur[idx] : 0;
    __syncthreads();
    for (int d = 128; d > 0; d >>= 1) {
        if (t < d) l[t] += l[t + d];
        __syncthreads();
    }
    if (t == 0) bsum[blockIdx.x] = l[0];
}

// stage 2: exclusive scan of 391 block sums (single block)
__global__ void scan2_kernel(const int* __restrict__ bsum, int* __restrict__ bbase,
                             int* __restrict__ offset) {
    __shared__ int l[512];
    const int t = threadIdx.x;
    const int v = (t < NBLK) ? bsum[t] : 0;
    l[t] = v;
    __syncthreads();
    for (int d = 1; d < 512; d <<= 1) {
        int u = l[t];
        if (t >= d) u += l[t - d];
        __syncthreads();
        l[t] = u;
        __syncthreads();
    }
    if (t < NBLK) bbase[t] = l[t] - v;
    if (t == NBLK - 1) offset[N_NODES] = l[t];   // total binned edges
}

// stage 3: block-local exclusive scan + base -> offset[], cur[] (fill cursor)
__global__ void scan3_kernel(int* __restrict__ cur, const int* __restrict__ bbase,
                             int* __restrict__ offset) {
    __shared__ int l[256];
    const int t = threadIdx.x;
    const int idx = blockIdx.x * 256 + t;
    const int v = (idx < N_NODES) ? cur[idx] : 0;
    l[t] = v;
    __syncthreads();
    for (int d = 1; d < 256; d <<= 1) {
        int u = l[t];
        if (t >= d) u += l[t - d];
        __syncthreads();
        l[t] = u;
        __syncthreads();
    }
    if (idx < N_NODES) {
        const int excl = bbase[blockIdx.x] + l[t] - v;
        offset[idx] = excl;
        cur[idx] = excl;
    }
}

// position-scatter from bins: csr writes confined to ~100KB window per bucket
__global__ void fill2_kernel(const int* __restrict__ bsrc, const int* __restrict__ bdst,
                             const int* __restrict__ bcnt,
                             int* __restrict__ cur, int* __restrict__ csr) {
    const int i = blockIdx.x * 256 + threadIdx.x;
    const int bucket = i >> BSH;
    const int slot = i & (BCAP - 1);
    if (slot < bcnt[bucket]) {
        const int pos = atomicAdd(cur + bdst[i], 1);
        csr[pos] = bsrc[i];
    }
}

// ---------------------------------------------------------------------------
// hout[n] = bf16( x[n] + sum_{s in N(n)} x[s] ).  One wave per node, lane=feature.
// ---------------------------------------------------------------------------
__global__ void agg_kernel(const bf16_t* __restrict__ x,
                           const int* __restrict__ offset,
                           const int* __restrict__ csr,
                           bf16_t* __restrict__ hout) {
    const int node = (blockIdx.x * 256 + threadIdx.x) >> 6;   // grid sized exactly
    const int f = threadIdx.x & 63;
    const int o0 = offset[node];
    const int o1 = offset[node + 1];

    float acc = (float)x[node * 64 + f];
    for (int i = o0; i < o1; i += 64) {
        const int cnt = (o1 - i < 64) ? (o1 - i) : 64;
        int s = 0;
        if (i + f < o1) s = csr[i + f];
        for (int j = 0; j < cnt; ++j) {
            const int sj = __shfl(s, j);                      // uniform broadcast
            acc += (float)x[sj * 64 + f];
        }
    }
    hout[node * 64 + f] = (bf16_t)acc;
}

// ---------------------------------------------------------------------------
// xout = bf16( relu( relu(hin @ wa + ba) @ wb + bb ) )
// Block=256 (4 waves), wave w: rows [tile*64+w*16, +16). MFMA 16x16x32 bf16.
// ---------------------------------------------------------------------------
__global__ void mlp_kernel(const bf16_t* __restrict__ hin,
                           const float* __restrict__ wa, const float* __restrict__ ba,
                           const float* __restrict__ wb, const float* __restrict__ bb,
                           bf16_t* __restrict__ xout) {
    __shared__ __align__(16) bf16_t h1s[4][16][72];

    const int tid  = threadIdx.x;
    const int wv   = tid >> 6;
    const int lane = tid & 63;
    const int l15  = lane & 15;
    const int quad = lane >> 4;

    bf16x8 bfa[4][2], bfb[4][2];
    float  bav[4], bbv[4];
#pragma unroll
    for (int ct = 0; ct < 4; ++ct) {
        const int n = ct * 16 + l15;
#pragma unroll
        for (int ks = 0; ks < 2; ++ks) {
            bf16x8 t1, t2;
#pragma unroll
            for (int j = 0; j < 8; ++j) {
                const int k = ks * 32 + quad * 8 + j;
                t1[j] = (bf16_t)wa[k * 64 + n];
                t2[j] = (bf16_t)wb[k * 64 + n];
            }
            bfa[ct][ks] = t1;
            bfb[ct][ks] = t2;
        }
        bav[ct] = ba[n];
        bbv[ct] = bb[n];
    }

    const int ntiles = (N_NODES + 63) / 64;   // 1563
    for (int tile = blockIdx.x; tile < ntiles; tile += gridDim.x) {
        const int rowa = tile * 64 + wv * 16 + l15;
        const int rowc = rowa < N_NODES ? rowa : N_NODES - 1;

        bf16x8 af[2];
#pragma unroll
        for (int ks = 0; ks < 2; ++ks)
            af[ks] = *(const bf16x8*)(hin + rowc * 64 + ks * 32 + quad * 8);

#pragma unroll
        for (int ct = 0; ct < 4; ++ct) {
            f32x4 acc = {0.f, 0.f, 0.f, 0.f};
            acc = __builtin_amdgcn_mfma_f32_16x16x32_bf16(af[0], bfa[ct][0], acc, 0, 0, 0);
            acc = __builtin_amdgcn_mfma_f32_16x16x32_bf16(af[1], bfa[ct][1], acc, 0, 0, 0);
#pragma unroll
            for (int r = 0; r < 4; ++r) {
                float h = acc[r] + bav[ct];
                h = h > 0.f ? h : 0.f;
                h1s[wv][quad * 4 + r][ct * 16 + l15] = (bf16_t)h;
            }
        }
        __syncthreads();

        bf16x8 a2[2];
#pragma unroll
        for (int ks = 0; ks < 2; ++ks)
            a2[ks] = *(const bf16x8*)(&h1s[wv][l15][ks * 32 + quad * 8]);

#pragma unroll
        for (int ct = 0; ct < 4; ++ct) {
            f32x4 acc = {0.f, 0.f, 0.f, 0.f};
            acc = __builtin_amdgcn_mfma_f32_16x16x32_bf16(a2[0], bfb[ct][0], acc, 0, 0, 0);
            acc = __builtin_amdgcn_mfma_f32_16x16x32_bf16(a2[1], bfb[ct][1], acc, 0, 0, 0);
#pragma unroll
            for (int r = 0; r < 4; ++r) {
                const int orow = tile * 64 + wv * 16 + quad * 4 + r;
                if (orow < N_NODES) {
                    float h = acc[r] + bbv[ct];
                    h = h > 0.f ? h : 0.f;
                    xout[orow * 64 + ct * 16 + l15] = (bf16_t)h;
                }
            }
        }
        __syncthreads();
    }
}

// ---------------------------------------------------------------------------
__global__ void pool_kernel(const bf16_t* __restrict__ x,
                            const int* __restrict__ batch,
                            float* __restrict__ gsum) {
    const int f  = threadIdx.x & 63;
    const int sg = threadIdx.x >> 6;
    const int n0 = blockIdx.x * 512 + sg * 128;
    const int n1 = (n0 + 128 < N_NODES) ? (n0 + 128) : N_NODES;
    float acc = 0.f;
    int cur = -1;
    for (int n = n0; n < n1; ++n) {
        const int g = batch[n];
        if (g != cur) {
            if (cur >= 0) unsafeAtomicAdd(gsum + cur * 64 + f, acc);
            acc = 0.f;
            cur = g;
        }
        acc += (float)x[n * 64 + f];
    }
    if (cur >= 0) unsafeAtomicAdd(gsum + cur * 64 + f, acc);
}

__global__ void cls_kernel(const float* __restrict__ gsum,
                           const int* __restrict__ batch,
                           const float* __restrict__ wc, const float* __restrict__ bc,
                           float* __restrict__ out) {
    const int g = blockIdx.x;
    const int c = threadIdx.x;
    if (c >= N_CLS) return;
    int lo = 0, hi = N_NODES;
    while (lo < hi) { const int m = (lo + hi) >> 1; if (batch[m] < g) lo = m + 1; else hi = m; }
    const int lb = lo;
    lo = 0; hi = N_NODES;
    while (lo < hi) { const int m = (lo + hi) >> 1; if (batch[m] <= g) lo = m + 1; else hi = m; }
    const int cnt = lo - lb;
    const float inv = 1.f / (float)(cnt > 1 ? cnt : 1);
    float acc = bc[c];
    for (int k = 0; k < 64; ++k)
        acc += gsum[g * 64 + k] * inv * wc[k * N_CLS + c];
    out[g * N_CLS + c] = acc;
}

// ---------------------------------------------------------------------------
extern "C" void kernel_launch(void* const* d_in, const int* in_sizes, int n_in,
                              void* d_out, int out_size, void* d_ws, size_t ws_size,
                              hipStream_t stream) {
    const float* x   = (const float*)d_in[0];
    const float* w1a = (const float*)d_in[1];
    const float* b1a = (const float*)d_in[2];
    const float* w1b = (const float*)d_in[3];
    const float* b1b = (const float*)d_in[4];
    const float* w2a = (const float*)d_in[5];
    const float* b2a = (const float*)d_in[6];
    const float* w2b = (const float*)d_in[7];
    const float* b2b = (const float*)d_in[8];
    const float* w3a = (const float*)d_in[9];
    const float* b3a = (const float*)d_in[10];
    const float* w3b = (const float*)d_in[11];
    const float* b3b = (const float*)d_in[12];
    const float* wc  = (const float*)d_in[13];
    const float* bc  = (const float*)d_in[14];
    const int*   ei    = (const int*)d_in[15];
    const int*   batch = (const int*)d_in[16];
    float* out = (float*)d_out;

    // workspace layout (~56.9 MB, 16B-aligned)
    char*   ws     = (char*)d_ws;
    int*    cur    = (int*)ws;                      // 400,000 B
    int*    bcnt   = (int*)(ws + 400000);           // 196 B (zeroed with cur)
    int*    offset = (int*)(ws + 400208);           // 400,004 B
    int*    csr    = (int*)(ws + 800224);           // 4,800,000 B
    int*    bsrc   = (int*)(ws + 5600224);          // 49*32768*4 = 6,422,528 B
    int*    bdst   = (int*)(ws + 12022752);         // 6,422,528 B
    bf16_t* xbf    = (bf16_t*)(ws + 18445280);      // 12,800,000 B
    bf16_t* h      = (bf16_t*)(ws + 31245280);      // 12,800,000 B
    bf16_t* xA     = (bf16_t*)(ws + 44045280);      // 12,800,000 B
    int*    bsum   = (int*)(ws + 56845280);         // 1564 B
    int*    bbase  = (int*)(ws + 56846848);         // 1564 B
    float*  gsum   = (float*)(ws + 56848416);       // 32,768 B

    const int e4grid  = (N_EDGES / 4 + 255) / 256;  // 1172
    const int bgrid   = (NBUCK * BCAP) / 256;       // 6272
    const int agrid   = (N_NODES * 64) / 256;       // 25000 (exact)
    const int mlpgrid = 512;

    // x -> bf16 (independent of CSR build)
    tobf_kernel<<<(N_NODES * 64) / (256 * 8), 256, 0, stream>>>(x, xbf);

    // CSR build (once, reused 3x)
    hipMemsetAsync(cur, 0, 400208, stream);         // cur + bcnt
    binA_kernel<<<e4grid, 256, 0, stream>>>(ei, bcnt, bsrc, bdst);
    deg2_kernel<<<bgrid, 256, 0, stream>>>(bdst, bcnt, cur);
    scan1_kernel<<<NBLK, 256, 0, stream>>>(cur, bsum);
    scan2_kernel<<<1, 512, 0, stream>>>(bsum, bbase, offset);
    scan3_kernel<<<NBLK, 256, 0, stream>>>(cur, bbase, offset);
    fill2_kernel<<<bgrid, 256, 0, stream>>>(bsrc, bdst, bcnt, cur, csr);

    // layer 1
    agg_kernel<<<agrid, 256, 0, stream>>>(xbf, offset, csr, h);
    mlp_kernel<<<mlpgrid, 256, 0, stream>>>(h, w1a, b1a, w1b, b1b, xA);
    // layer 2
    agg_kernel<<<agrid, 256, 0, stream>>>(xA, offset, csr, h);
    mlp_kernel<<<mlpgrid, 256, 0, stream>>>(h, w2a, b2a, w2b, b2b, xA);
    // layer 3
    agg_kernel<<<agrid, 256, 0, stream>>>(xA, offset, csr, h);
    mlp_kernel<<<mlpgrid, 256, 0, stream>>>(h, w3a, b3a, w3b, b3b, xA);

    // pool + classify
    hipMemsetAsync(gsum, 0, 32768, stream);
    pool_kernel<<<(N_NODES + 511) / 512, 256, 0, stream>>>(xA, batch, gsum);
    cls_kernel<<<N_GRAPH, 64, 0, stream>>>(gsum, batch, wc, bc, out);
}

// Round 6
// 444.527 us; speedup vs baseline: 2.8625x; 1.2573x over previous
//
#include <hip/hip_runtime.h>
#include <hip/hip_bf16.h>

// GIN: 3x [CSR gather-sum + MLP(64->64->64) + relu] + mean-pool(128) + linear(64->10)
// x converted to bf16 once; agg gathers bf16 with 8-way ILP, f32 accumulate.
// CSR built per launch via 49-bucket radix binning, reused 3x.
// MLP: one 64-row tile per block, LDS-staged bf16 weight fragments, coalesced IO.

#define N_NODES 100000
#define N_EDGES 1200000
#define N_GRAPH 128
#define N_CLS   10
#define NBLK    391        // ceil(N_NODES/256)
#define NBUCK   49         // dst >> 11
#define BCAP    32768      // per-bucket pair capacity
#define BSH     15         // log2(BCAP)

typedef __bf16 bf16_t;
typedef __bf16 bf16x8 __attribute__((ext_vector_type(8)));
typedef float  f32x4  __attribute__((ext_vector_type(4)));

// ---------------- x -> bf16 ----------------
__global__ void tobf_kernel(const float* __restrict__ x, bf16_t* __restrict__ xb) {
    const int i = (blockIdx.x * 256 + threadIdx.x) * 8;
    const f32x4 a = *(const f32x4*)(x + i);
    const f32x4 b = *(const f32x4*)(x + i + 4);
    bf16x8 o;
#pragma unroll
    for (int j = 0; j < 4; ++j) { o[j] = (bf16_t)a[j]; o[4 + j] = (bf16_t)b[j]; }
    *(bf16x8*)(xb + i) = o;
}

// ---------------- CSR build: bucket binning ----------------
__global__ void binA_kernel(const int* __restrict__ ei,
                            int* __restrict__ bcnt,
                            int* __restrict__ bsrc, int* __restrict__ bdst) {
    __shared__ int lcnt[NBUCK];
    __shared__ int lbase[NBUCK];
    const int t = threadIdx.x;
    if (t < NBUCK) lcnt[t] = 0;
    __syncthreads();
    const int e0 = (blockIdx.x * 256 + t) * 4;
    int4 s4, d4; int b[4], r[4];
    const bool valid = e0 < N_EDGES;
    if (valid) {
        s4 = *(const int4*)(ei + e0);
        d4 = *(const int4*)(ei + N_EDGES + e0);
        b[0] = d4.x >> 11; b[1] = d4.y >> 11; b[2] = d4.z >> 11; b[3] = d4.w >> 11;
        r[0] = atomicAdd(&lcnt[b[0]], 1);
        r[1] = atomicAdd(&lcnt[b[1]], 1);
        r[2] = atomicAdd(&lcnt[b[2]], 1);
        r[3] = atomicAdd(&lcnt[b[3]], 1);
    }
    __syncthreads();
    if (t < NBUCK) {
        const int c = lcnt[t];
        lbase[t] = c ? atomicAdd(&bcnt[t], c) : 0;
    }
    __syncthreads();
    if (valid) {
        const int ss[4] = {s4.x, s4.y, s4.z, s4.w};
        const int dd[4] = {d4.x, d4.y, d4.z, d4.w};
#pragma unroll
        for (int j = 0; j < 4; ++j) {
            const int slot = lbase[b[j]] + r[j];
            if (slot < BCAP) {
                bsrc[(b[j] << BSH) + slot] = ss[j];
                bdst[(b[j] << BSH) + slot] = dd[j];
            }
        }
    }
}

__global__ void deg2_kernel(const int* __restrict__ bdst, const int* __restrict__ bcnt,
                            int* __restrict__ cur) {
    const int i = blockIdx.x * 256 + threadIdx.x;
    const int bucket = i >> BSH;
    const int slot = i & (BCAP - 1);
    if (slot < bcnt[bucket])
        atomicAdd(cur + bdst[i], 1);
}

__global__ void scan1_kernel(const int* __restrict__ cur, int* __restrict__ bsum) {
    __shared__ int l[256];
    const int t = threadIdx.x;
    const int idx = blockIdx.x * 256 + t;
    l[t] = (idx < N_NODES) ? cur[idx] : 0;
    __syncthreads();
    for (int d = 128; d > 0; d >>= 1) {
        if (t < d) l[t] += l[t + d];
        __syncthreads();
    }
    if (t == 0) bsum[blockIdx.x] = l[0];
}

__global__ void scan2_kernel(const int* __restrict__ bsum, int* __restrict__ bbase,
                             int* __restrict__ offset) {
    __shared__ int l[512];
    const int t = threadIdx.x;
    const int v = (t < NBLK) ? bsum[t] : 0;
    l[t] = v;
    __syncthreads();
    for (int d = 1; d < 512; d <<= 1) {
        int u = l[t];
        if (t >= d) u += l[t - d];
        __syncthreads();
        l[t] = u;
        __syncthreads();
    }
    if (t < NBLK) bbase[t] = l[t] - v;
    if (t == NBLK - 1) offset[N_NODES] = l[t];
}

__global__ void scan3_kernel(int* __restrict__ cur, const int* __restrict__ bbase,
                             int* __restrict__ offset) {
    __shared__ int l[256];
    const int t = threadIdx.x;
    const int idx = blockIdx.x * 256 + t;
    const int v = (idx < N_NODES) ? cur[idx] : 0;
    l[t] = v;
    __syncthreads();
    for (int d = 1; d < 256; d <<= 1) {
        int u = l[t];
        if (t >= d) u += l[t - d];
        __syncthreads();
        l[t] = u;
        __syncthreads();
    }
    if (idx < N_NODES) {
        const int excl = bbase[blockIdx.x] + l[t] - v;
        offset[idx] = excl;
        cur[idx] = excl;
    }
}

__global__ void fill2_kernel(const int* __restrict__ bsrc, const int* __restrict__ bdst,
                             const int* __restrict__ bcnt,
                             int* __restrict__ cur, int* __restrict__ csr) {
    const int i = blockIdx.x * 256 + threadIdx.x;
    const int bucket = i >> BSH;
    const int slot = i & (BCAP - 1);
    if (slot < bcnt[bucket]) {
        const int pos = atomicAdd(cur + bdst[i], 1);
        csr[pos] = bsrc[i];
    }
}

// ---------------------------------------------------------------------------
// hout[n] = bf16( x[n] + sum_{s in N(n)} x[s] ).  One wave per node, lane=feature.
// 8-way unrolled gather: 8 independent loads in flight per wave.
// ---------------------------------------------------------------------------
__global__ void agg_kernel(const bf16_t* __restrict__ x,
                           const int* __restrict__ offset,
                           const int* __restrict__ csr,
                           bf16_t* __restrict__ hout) {
    const int node = (blockIdx.x * 256 + threadIdx.x) >> 6;
    const int f = threadIdx.x & 63;
    const int o0 = offset[node];
    const int o1 = offset[node + 1];

    float acc = (float)x[node * 64 + f];
    for (int i = o0; i < o1; i += 64) {
        const int cnt = (o1 - i < 64) ? (o1 - i) : 64;
        int s = 0;
        if (i + f < o1) s = csr[i + f];
        int j = 0;
        for (; j + 8 <= cnt; j += 8) {
            const int s0 = __shfl(s, j + 0), s1 = __shfl(s, j + 1);
            const int s2 = __shfl(s, j + 2), s3 = __shfl(s, j + 3);
            const int s4 = __shfl(s, j + 4), s5 = __shfl(s, j + 5);
            const int s6 = __shfl(s, j + 6), s7 = __shfl(s, j + 7);
            const float v0 = (float)x[s0 * 64 + f], v1 = (float)x[s1 * 64 + f];
            const float v2 = (float)x[s2 * 64 + f], v3 = (float)x[s3 * 64 + f];
            const float v4 = (float)x[s4 * 64 + f], v5 = (float)x[s5 * 64 + f];
            const float v6 = (float)x[s6 * 64 + f], v7 = (float)x[s7 * 64 + f];
            acc += ((v0 + v1) + (v2 + v3)) + ((v4 + v5) + (v6 + v7));
        }
        if (j + 4 <= cnt) {
            const int s0 = __shfl(s, j + 0), s1 = __shfl(s, j + 1);
            const int s2 = __shfl(s, j + 2), s3 = __shfl(s, j + 3);
            const float v0 = (float)x[s0 * 64 + f], v1 = (float)x[s1 * 64 + f];
            const float v2 = (float)x[s2 * 64 + f], v3 = (float)x[s3 * 64 + f];
            acc += (v0 + v1) + (v2 + v3);
            j += 4;
        }
        for (; j < cnt; ++j) {
            const int sj = __shfl(s, j);
            acc += (float)x[sj * 64 + f];
        }
    }
    hout[node * 64 + f] = (bf16_t)acc;
}

// ---------------------------------------------------------------------------
// xout = bf16( relu( relu(hin @ wa + ba) @ wb + bb ) )
// One 64-row tile per block (grid=1563). Weights staged to LDS in MFMA
// fragment layout (frag read = 1 ds_read_b128). Per-wave LDS tiles, no
// barriers in compute. Coalesced bf16x8 output via LDS transpose tile.
// A: A[m=lane&15][k=quad*8+j]; B: B[k=quad*8+j][n=ct*16+l15]; C/D: row=quad*4+r, col.
// ---------------------------------------------------------------------------
__global__ void mlp_kernel(const bf16_t* __restrict__ hin,
                           const float* __restrict__ wa, const float* __restrict__ ba,
                           const float* __restrict__ wb, const float* __restrict__ bb,
                           bf16_t* __restrict__ xout) {
    __shared__ __align__(16) bf16_t wfrag[2][8][64][8];  // [mat][ct*2+ks][lane][j]
    __shared__ __align__(16) bf16_t hs[4][16][72];       // h1 (per-wave)
    __shared__ __align__(16) bf16_t hs2[4][16][72];      // h2 (per-wave)
    __shared__ float biasA[64], biasB[64];

    const int tid  = threadIdx.x;
    const int wv   = tid >> 6;
    const int lane = tid & 63;
    const int l15  = lane & 15;
    const int quad = lane >> 4;

    // ---- stage weights: coalesced f32x4 reads -> bf16 fragment-layout LDS ----
    {
        const int k  = tid >> 2;                 // 0..63
        const int n0 = (tid & 3) << 4;           // 0,16,32,48
        const int ks = k >> 5, qd = (k >> 3) & 3, jj = k & 7;
        const int fi = ((n0 >> 4) << 1) + ks;    // ct*2+ks
#pragma unroll
        for (int m = 0; m < 2; ++m) {
            const float* w = m ? wb : wa;
            const f32x4 v0 = *(const f32x4*)(w + k * 64 + n0);
            const f32x4 v1 = *(const f32x4*)(w + k * 64 + n0 + 4);
            const f32x4 v2 = *(const f32x4*)(w + k * 64 + n0 + 8);
            const f32x4 v3 = *(const f32x4*)(w + k * 64 + n0 + 12);
#pragma unroll
            for (int l = 0; l < 4; ++l) {
                wfrag[m][fi][qd * 16 + l][jj]      = (bf16_t)v0[l];
                wfrag[m][fi][qd * 16 + 4 + l][jj]  = (bf16_t)v1[l];
                wfrag[m][fi][qd * 16 + 8 + l][jj]  = (bf16_t)v2[l];
                wfrag[m][fi][qd * 16 + 12 + l][jj] = (bf16_t)v3[l];
            }
        }
        if (tid < 64) biasA[tid] = ba[tid];
        else if (tid < 128) biasB[tid - 64] = bb[tid - 64];
    }
    __syncthreads();

    const int rb = blockIdx.x * 64 + wv * 16;    // this wave's row base
    const int rowa = rb + l15;
    const int rowc = rowa < N_NODES ? rowa : N_NODES - 1;

    // A fragments (16B vector loads)
    bf16x8 af[2];
#pragma unroll
    for (int ks = 0; ks < 2; ++ks)
        af[ks] = *(const bf16x8*)(hin + rowc * 64 + ks * 32 + quad * 8);

    const float bA = biasA[quad * 16 + l15 - quad * 16 + l15];  // placeholder avoided below

    // GEMM1 -> relu -> hs
#pragma unroll
    for (int ct = 0; ct < 4; ++ct) {
        const bf16x8 b0 = *(const bf16x8*)&wfrag[0][ct * 2 + 0][lane][0];
        const bf16x8 b1 = *(const bf16x8*)&wfrag[0][ct * 2 + 1][lane][0];
        f32x4 acc = {0.f, 0.f, 0.f, 0.f};
        acc = __builtin_amdgcn_mfma_f32_16x16x32_bf16(af[0], b0, acc, 0, 0, 0);
        acc = __builtin_amdgcn_mfma_f32_16x16x32_bf16(af[1], b1, acc, 0, 0, 0);
        const float bv = biasA[ct * 16 + l15];
#pragma unroll
        for (int r = 0; r < 4; ++r) {
            float h = acc[r] + bv;
            h = h > 0.f ? h : 0.f;
            hs[wv][quad * 4 + r][ct * 16 + l15] = (bf16_t)h;
        }
    }

    // h1 -> A layout (per-wave, compiler inserts lgkm waits)
    bf16x8 a2[2];
#pragma unroll
    for (int ks = 0; ks < 2; ++ks)
        a2[ks] = *(const bf16x8*)(&hs[wv][l15][ks * 32 + quad * 8]);

    // GEMM2 -> relu -> hs2
#pragma unroll
    for (int ct = 0; ct < 4; ++ct) {
        const bf16x8 b0 = *(const bf16x8*)&wfrag[1][ct * 2 + 0][lane][0];
        const bf16x8 b1 = *(const bf16x8*)&wfrag[1][ct * 2 + 1][lane][0];
        f32x4 acc = {0.f, 0.f, 0.f, 0.f};
        acc = __builtin_amdgcn_mfma_f32_16x16x32_bf16(a2[0], b0, acc, 0, 0, 0);
        acc = __builtin_amdgcn_mfma_f32_16x16x32_bf16(a2[1], b1, acc, 0, 0, 0);
        const float bv = biasB[ct * 16 + l15];
#pragma unroll
        for (int r = 0; r < 4; ++r) {
            float h = acc[r] + bv;
            h = h > 0.f ? h : 0.f;
            hs2[wv][quad * 4 + r][ct * 16 + l15] = (bf16_t)h;
        }
    }

    // coalesced store: 8 rows x 128B contiguous per instruction
    const int colg = (lane & 7) * 8;
#pragma unroll
    for (int sx = 0; sx < 2; ++sx) {
        const int r16 = (lane >> 3) + 8 * sx;
        const int grow = rb + r16;
        const bf16x8 v = *(const bf16x8*)&hs2[wv][r16][colg];
        if (grow < N_NODES)
            *(bf16x8*)(xout + grow * 64 + colg) = v;
    }
}

// ---------------------------------------------------------------------------
__global__ void pool_kernel(const bf16_t* __restrict__ x,
                            const int* __restrict__ batch,
                            float* __restrict__ gsum) {
    const int f  = threadIdx.x & 63;
    const int sg = threadIdx.x >> 6;
    const int n0 = blockIdx.x * 512 + sg * 128;
    const int n1 = (n0 + 128 < N_NODES) ? (n0 + 128) : N_NODES;
    float acc = 0.f;
    int cur = -1;
    for (int n = n0; n < n1; ++n) {
        const int g = batch[n];
        if (g != cur) {
            if (cur >= 0) unsafeAtomicAdd(gsum + cur * 64 + f, acc);
            acc = 0.f;
            cur = g;
        }
        acc += (float)x[n * 64 + f];
    }
    if (cur >= 0) unsafeAtomicAdd(gsum + cur * 64 + f, acc);
}

__global__ void cls_kernel(const float* __restrict__ gsum,
                           const int* __restrict__ batch,
                           const float* __restrict__ wc, const float* __restrict__ bc,
                           float* __restrict__ out) {
    const int g = blockIdx.x;
    const int c = threadIdx.x;
    if (c >= N_CLS) return;
    int lo = 0, hi = N_NODES;
    while (lo < hi) { const int m = (lo + hi) >> 1; if (batch[m] < g) lo = m + 1; else hi = m; }
    const int lb = lo;
    lo = 0; hi = N_NODES;
    while (lo < hi) { const int m = (lo + hi) >> 1; if (batch[m] <= g) lo = m + 1; else hi = m; }
    const int cnt = lo - lb;
    const float inv = 1.f / (float)(cnt > 1 ? cnt : 1);
    float acc = bc[c];
    for (int k = 0; k < 64; ++k)
        acc += gsum[g * 64 + k] * inv * wc[k * N_CLS + c];
    out[g * N_CLS + c] = acc;
}

// ---------------------------------------------------------------------------
extern "C" void kernel_launch(void* const* d_in, const int* in_sizes, int n_in,
                              void* d_out, int out_size, void* d_ws, size_t ws_size,
                              hipStream_t stream) {
    const float* x   = (const float*)d_in[0];
    const float* w1a = (const float*)d_in[1];
    const float* b1a = (const float*)d_in[2];
    const float* w1b = (const float*)d_in[3];
    const float* b1b = (const float*)d_in[4];
    const float* w2a = (const float*)d_in[5];
    const float* b2a = (const float*)d_in[6];
    const float* w2b = (const float*)d_in[7];
    const float* b2b = (const float*)d_in[8];
    const float* w3a = (const float*)d_in[9];
    const float* b3a = (const float*)d_in[10];
    const float* w3b = (const float*)d_in[11];
    const float* b3b = (const float*)d_in[12];
    const float* wc  = (const float*)d_in[13];
    const float* bc  = (const float*)d_in[14];
    const int*   ei    = (const int*)d_in[15];
    const int*   batch = (const int*)d_in[16];
    float* out = (float*)d_out;

    // workspace layout (~56.9 MB, 16B-aligned)
    char*   ws     = (char*)d_ws;
    int*    cur    = (int*)ws;                      // 400,000 B
    int*    bcnt   = (int*)(ws + 400000);           // 196 B (zeroed with cur)
    int*    offset = (int*)(ws + 400208);           // 400,004 B
    int*    csr    = (int*)(ws + 800224);           // 4,800,000 B
    int*    bsrc   = (int*)(ws + 5600224);          // 6,422,528 B
    int*    bdst   = (int*)(ws + 12022752);         // 6,422,528 B
    bf16_t* xbf    = (bf16_t*)(ws + 18445280);      // 12,800,000 B
    bf16_t* h      = (bf16_t*)(ws + 31245280);      // 12,800,000 B
    bf16_t* xA     = (bf16_t*)(ws + 44045280);      // 12,800,000 B
    int*    bsum   = (int*)(ws + 56845280);         // 1564 B
    int*    bbase  = (int*)(ws + 56846848);         // 1564 B
    float*  gsum   = (float*)(ws + 56848416);       // 32,768 B

    const int e4grid  = (N_EDGES / 4 + 255) / 256;  // 1172
    const int bgrid   = (NBUCK * BCAP) / 256;       // 6272
    const int agrid   = (N_NODES * 64) / 256;       // 25000 (exact)
    const int mlpgrid = (N_NODES + 63) / 64;        // 1563

    // x -> bf16
    tobf_kernel<<<(N_NODES * 64) / (256 * 8), 256, 0, stream>>>(x, xbf);

    // CSR build (once, reused 3x)
    hipMemsetAsync(cur, 0, 400208, stream);         // cur + bcnt
    binA_kernel<<<e4grid, 256, 0, stream>>>(ei, bcnt, bsrc, bdst);
    deg2_kernel<<<bgrid, 256, 0, stream>>>(bdst, bcnt, cur);
    scan1_kernel<<<NBLK, 256, 0, stream>>>(cur, bsum);
    scan2_kernel<<<1, 512, 0, stream>>>(bsum, bbase, offset);
    scan3_kernel<<<NBLK, 256, 0, stream>>>(cur, bbase, offset);
    fill2_kernel<<<bgrid, 256, 0, stream>>>(bsrc, bdst, bcnt, cur, csr);

    // layer 1
    agg_kernel<<<agrid, 256, 0, stream>>>(xbf, offset, csr, h);
    mlp_kernel<<<mlpgrid, 256, 0, stream>>>(h, w1a, b1a, w1b, b1b, xA);
    // layer 2
    agg_kernel<<<agrid, 256, 0, stream>>>(xA, offset, csr, h);
    mlp_kernel<<<mlpgrid, 256, 0, stream>>>(h, w2a, b2a, w2b, b2b, xA);
    // layer 3
    agg_kernel<<<agrid, 256, 0, stream>>>(xA, offset, csr, h);
    mlp_kernel<<<mlpgrid, 256, 0, stream>>>(h, w3a, b3a, w3b, b3b, xA);

    // pool + classify
    hipMemsetAsync(gsum, 0, 32768, stream);
    pool_kernel<<<(N_NODES + 511) / 512, 256, 0, stream>>>(xA, batch, gsum);
    cls_kernel<<<N_GRAPH, 64, 0, stream>>>(gsum, batch, wc, bc, out);
}

// Round 7
// 380.008 us; speedup vs baseline: 3.3485x; 1.1698x over previous
//
#include <hip/hip_runtime.h>
#include <hip/hip_bf16.h>

// GIN: 3x [CSR gather-sum + MLP(64->64->64) + relu] + mean-pool(128) + linear(64->10)
// x -> bf16 once; agg gathers bf16 with 8-way ILP, f32 accumulate.
// CSR built per launch: 391-bucket binning (packed pairs) + per-bucket
// counting sort (one WG per bucket, LDS histogram/scan/cursors) -> offset+csr
// with ~12KB contiguous write windows. Reused for all 3 layers.

#define N_NODES 100000
#define N_EDGES 1200000
#define N_GRAPH 128
#define N_CLS   10
#define NBUCK   391        // dst >> 8  (99999>>8 = 390)
#define BCAP    4096       // per-bucket capacity (mean 3070, +18 sigma)
#define BSH     12         // log2(BCAP)

typedef __bf16 bf16_t;
typedef __bf16 bf16x8 __attribute__((ext_vector_type(8)));
typedef float  f32x4  __attribute__((ext_vector_type(4)));

// ---------------- x -> bf16 ----------------
__global__ void tobf_kernel(const float* __restrict__ x, bf16_t* __restrict__ xb) {
    const int i = (blockIdx.x * 256 + threadIdx.x) * 8;
    const f32x4 a = *(const f32x4*)(x + i);
    const f32x4 b = *(const f32x4*)(x + i + 4);
    bf16x8 o;
#pragma unroll
    for (int j = 0; j < 4; ++j) { o[j] = (bf16_t)a[j]; o[4 + j] = (bf16_t)b[j]; }
    *(bf16x8*)(xb + i) = o;
}

// ---------------- CSR build ----------------
// Bin packed (src<<8 | dst&255) by dst>>8. LDS histogram -> one global cursor
// reservation per touched bucket -> contiguous packed writes.
__global__ void binA_kernel(const int* __restrict__ ei,
                            int* __restrict__ bcnt,
                            int* __restrict__ bpair) {
    __shared__ int lcnt[NBUCK];
    __shared__ int lbase[NBUCK];
    const int t = threadIdx.x;
    for (int b = t; b < NBUCK; b += 256) lcnt[b] = 0;
    __syncthreads();
    const int e0 = (blockIdx.x * 256 + t) * 4;
    int4 s4, d4; int b[4], r[4];
    const bool valid = e0 < N_EDGES;               // N_EDGES % 4 == 0
    if (valid) {
        s4 = *(const int4*)(ei + e0);
        d4 = *(const int4*)(ei + N_EDGES + e0);
        b[0] = d4.x >> 8; b[1] = d4.y >> 8; b[2] = d4.z >> 8; b[3] = d4.w >> 8;
        r[0] = atomicAdd(&lcnt[b[0]], 1);
        r[1] = atomicAdd(&lcnt[b[1]], 1);
        r[2] = atomicAdd(&lcnt[b[2]], 1);
        r[3] = atomicAdd(&lcnt[b[3]], 1);
    }
    __syncthreads();
    for (int bb = t; bb < NBUCK; bb += 256) {
        const int c = lcnt[bb];
        lbase[bb] = c ? atomicAdd(&bcnt[bb], c) : 0;
    }
    __syncthreads();
    if (valid) {
        const int ss[4] = {s4.x, s4.y, s4.z, s4.w};
        const int dd[4] = {d4.x, d4.y, d4.z, d4.w};
#pragma unroll
        for (int j = 0; j < 4; ++j) {
            const int slot = lbase[b[j]] + r[j];
            if (slot < BCAP)                        // overflow guard (18 sigma)
                bpair[(b[j] << BSH) + slot] = (ss[j] << 8) | (dd[j] & 255);
        }
    }
}

// exclusive scan of 391 bucket counts -> cbase[]; offset[N] = total
__global__ void bscan_kernel(const int* __restrict__ bcnt, int* __restrict__ cbase,
                             int* __restrict__ offset) {
    __shared__ int l[512];
    const int t = threadIdx.x;
    const int v = (t < NBUCK) ? bcnt[t] : 0;
    l[t] = v;
    __syncthreads();
    for (int d = 1; d < 512; d <<= 1) {
        int u = l[t];
        if (t >= d) u += l[t - d];
        __syncthreads();
        l[t] = u;
        __syncthreads();
    }
    if (t < NBUCK) cbase[t] = l[t] - v;
    if (t == NBUCK - 1) offset[N_NODES] = l[t];
}

// one WG per bucket: LDS counting sort -> offset[] + csr (12KB write window)
__global__ void sortfill_kernel(const int* __restrict__ bpair,
                                const int* __restrict__ bcnt,
                                const int* __restrict__ cbase,
                                int* __restrict__ offset, int* __restrict__ csr) {
    __shared__ int hist[256];
    __shared__ int l[256];
    __shared__ int cursor[256];
    const int b = blockIdx.x;
    const int t = threadIdx.x;
    const int base = b << BSH;
    int cnt = bcnt[b];
    cnt = cnt < BCAP ? cnt : BCAP;

    hist[t] = 0;
    __syncthreads();
    for (int i = t; i < cnt; i += 256)
        atomicAdd(&hist[bpair[base + i] & 255], 1);
    __syncthreads();

    const int v = hist[t];
    l[t] = v;
    __syncthreads();
    for (int d = 1; d < 256; d <<= 1) {
        int u = l[t];
        if (t >= d) u += l[t - d];
        __syncthreads();
        l[t] = u;
        __syncthreads();
    }
    const int gpos = cbase[b] + l[t] - v;           // exclusive
    const int node = (b << 8) + t;
    if (node < N_NODES) offset[node] = gpos;
    cursor[t] = gpos;
    __syncthreads();

    for (int i = t; i < cnt; i += 256) {
        const int p = bpair[base + i];
        const int pos = atomicAdd(&cursor[p & 255], 1);
        csr[pos] = p >> 8;
    }
}

// ---------------------------------------------------------------------------
// hout[n] = bf16( x[n] + sum_{s in N(n)} x[s] ).  One wave per node, lane=feature.
// 8-way unrolled gather: 8 independent loads in flight per wave.
// ---------------------------------------------------------------------------
__global__ void agg_kernel(const bf16_t* __restrict__ x,
                           const int* __restrict__ offset,
                           const int* __restrict__ csr,
                           bf16_t* __restrict__ hout) {
    const int node = (blockIdx.x * 256 + threadIdx.x) >> 6;
    const int f = threadIdx.x & 63;
    const int o0 = offset[node];
    const int o1 = offset[node + 1];

    float acc = (float)x[node * 64 + f];
    for (int i = o0; i < o1; i += 64) {
        const int cnt = (o1 - i < 64) ? (o1 - i) : 64;
        int s = 0;
        if (i + f < o1) s = csr[i + f];
        int j = 0;
        for (; j + 8 <= cnt; j += 8) {
            const int s0 = __shfl(s, j + 0), s1 = __shfl(s, j + 1);
            const int s2 = __shfl(s, j + 2), s3 = __shfl(s, j + 3);
            const int s4 = __shfl(s, j + 4), s5 = __shfl(s, j + 5);
            const int s6 = __shfl(s, j + 6), s7 = __shfl(s, j + 7);
            const float v0 = (float)x[s0 * 64 + f], v1 = (float)x[s1 * 64 + f];
            const float v2 = (float)x[s2 * 64 + f], v3 = (float)x[s3 * 64 + f];
            const float v4 = (float)x[s4 * 64 + f], v5 = (float)x[s5 * 64 + f];
            const float v6 = (float)x[s6 * 64 + f], v7 = (float)x[s7 * 64 + f];
            acc += ((v0 + v1) + (v2 + v3)) + ((v4 + v5) + (v6 + v7));
        }
        if (j + 4 <= cnt) {
            const int s0 = __shfl(s, j + 0), s1 = __shfl(s, j + 1);
            const int s2 = __shfl(s, j + 2), s3 = __shfl(s, j + 3);
            const float v0 = (float)x[s0 * 64 + f], v1 = (float)x[s1 * 64 + f];
            const float v2 = (float)x[s2 * 64 + f], v3 = (float)x[s3 * 64 + f];
            acc += (v0 + v1) + (v2 + v3);
            j += 4;
        }
        for (; j < cnt; ++j) {
            const int sj = __shfl(s, j);
            acc += (float)x[sj * 64 + f];
        }
    }
    hout[node * 64 + f] = (bf16_t)acc;
}

// ---------------------------------------------------------------------------
// xout = bf16( relu( relu(hin @ wa + ba) @ wb + bb ) )
// One 64-row tile per block (grid=1563). Weights staged once to LDS in MFMA
// fragment layout; per-wave LDS tiles; coalesced bf16x8 output stores.
// ---------------------------------------------------------------------------
__global__ void mlp_kernel(const bf16_t* __restrict__ hin,
                           const float* __restrict__ wa, const float* __restrict__ ba,
                           const float* __restrict__ wb, const float* __restrict__ bb,
                           bf16_t* __restrict__ xout) {
    __shared__ __align__(16) bf16_t wfrag[2][8][64][8];  // [mat][ct*2+ks][lane][j]
    __shared__ __align__(16) bf16_t hs[4][16][72];
    __shared__ __align__(16) bf16_t hs2[4][16][72];
    __shared__ float biasA[64], biasB[64];

    const int tid  = threadIdx.x;
    const int wv   = tid >> 6;
    const int lane = tid & 63;
    const int l15  = lane & 15;
    const int quad = lane >> 4;

    {
        const int k  = tid >> 2;
        const int n0 = (tid & 3) << 4;
        const int ks = k >> 5, qd = (k >> 3) & 3, jj = k & 7;
        const int fi = ((n0 >> 4) << 1) + ks;
#pragma unroll
        for (int m = 0; m < 2; ++m) {
            const float* w = m ? wb : wa;
            const f32x4 v0 = *(const f32x4*)(w + k * 64 + n0);
            const f32x4 v1 = *(const f32x4*)(w + k * 64 + n0 + 4);
            const f32x4 v2 = *(const f32x4*)(w + k * 64 + n0 + 8);
            const f32x4 v3 = *(const f32x4*)(w + k * 64 + n0 + 12);
#pragma unroll
            for (int l = 0; l < 4; ++l) {
                wfrag[m][fi][qd * 16 + l][jj]      = (bf16_t)v0[l];
                wfrag[m][fi][qd * 16 + 4 + l][jj]  = (bf16_t)v1[l];
                wfrag[m][fi][qd * 16 + 8 + l][jj]  = (bf16_t)v2[l];
                wfrag[m][fi][qd * 16 + 12 + l][jj] = (bf16_t)v3[l];
            }
        }
        if (tid < 64) biasA[tid] = ba[tid];
        else if (tid < 128) biasB[tid - 64] = bb[tid - 64];
    }
    __syncthreads();

    const int rb = blockIdx.x * 64 + wv * 16;
    const int rowa = rb + l15;
    const int rowc = rowa < N_NODES ? rowa : N_NODES - 1;

    bf16x8 af[2];
#pragma unroll
    for (int ks = 0; ks < 2; ++ks)
        af[ks] = *(const bf16x8*)(hin + rowc * 64 + ks * 32 + quad * 8);

#pragma unroll
    for (int ct = 0; ct < 4; ++ct) {
        const bf16x8 b0 = *(const bf16x8*)&wfrag[0][ct * 2 + 0][lane][0];
        const bf16x8 b1 = *(const bf16x8*)&wfrag[0][ct * 2 + 1][lane][0];
        f32x4 acc = {0.f, 0.f, 0.f, 0.f};
        acc = __builtin_amdgcn_mfma_f32_16x16x32_bf16(af[0], b0, acc, 0, 0, 0);
        acc = __builtin_amdgcn_mfma_f32_16x16x32_bf16(af[1], b1, acc, 0, 0, 0);
        const float bv = biasA[ct * 16 + l15];
#pragma unroll
        for (int r = 0; r < 4; ++r) {
            float h = acc[r] + bv;
            h = h > 0.f ? h : 0.f;
            hs[wv][quad * 4 + r][ct * 16 + l15] = (bf16_t)h;
        }
    }

    bf16x8 a2[2];
#pragma unroll
    for (int ks = 0; ks < 2; ++ks)
        a2[ks] = *(const bf16x8*)(&hs[wv][l15][ks * 32 + quad * 8]);

#pragma unroll
    for (int ct = 0; ct < 4; ++ct) {
        const bf16x8 b0 = *(const bf16x8*)&wfrag[1][ct * 2 + 0][lane][0];
        const bf16x8 b1 = *(const bf16x8*)&wfrag[1][ct * 2 + 1][lane][0];
        f32x4 acc = {0.f, 0.f, 0.f, 0.f};
        acc = __builtin_amdgcn_mfma_f32_16x16x32_bf16(a2[0], b0, acc, 0, 0, 0);
        acc = __builtin_amdgcn_mfma_f32_16x16x32_bf16(a2[1], b1, acc, 0, 0, 0);
        const float bv = biasB[ct * 16 + l15];
#pragma unroll
        for (int r = 0; r < 4; ++r) {
            float h = acc[r] + bv;
            h = h > 0.f ? h : 0.f;
            hs2[wv][quad * 4 + r][ct * 16 + l15] = (bf16_t)h;
        }
    }

    const int colg = (lane & 7) * 8;
#pragma unroll
    for (int sx = 0; sx < 2; ++sx) {
        const int r16 = (lane >> 3) + 8 * sx;
        const int grow = rb + r16;
        const bf16x8 v = *(const bf16x8*)&hs2[wv][r16][colg];
        if (grow < N_NODES)
            *(bf16x8*)(xout + grow * 64 + colg) = v;
    }
}

// ---------------------------------------------------------------------------
__global__ void pool_kernel(const bf16_t* __restrict__ x,
                            const int* __restrict__ batch,
                            float* __restrict__ gsum) {
    const int f  = threadIdx.x & 63;
    const int sg = threadIdx.x >> 6;
    const int n0 = blockIdx.x * 512 + sg * 128;
    const int n1 = (n0 + 128 < N_NODES) ? (n0 + 128) : N_NODES;
    float acc = 0.f;
    int cur = -1;
    for (int n = n0; n < n1; ++n) {
        const int g = batch[n];
        if (g != cur) {
            if (cur >= 0) unsafeAtomicAdd(gsum + cur * 64 + f, acc);
            acc = 0.f;
            cur = g;
        }
        acc += (float)x[n * 64 + f];
    }
    if (cur >= 0) unsafeAtomicAdd(gsum + cur * 64 + f, acc);
}

__global__ void cls_kernel(const float* __restrict__ gsum,
                           const int* __restrict__ batch,
                           const float* __restrict__ wc, const float* __restrict__ bc,
                           float* __restrict__ out) {
    const int g = blockIdx.x;
    const int c = threadIdx.x;
    if (c >= N_CLS) return;
    int lo = 0, hi = N_NODES;
    while (lo < hi) { const int m = (lo + hi) >> 1; if (batch[m] < g) lo = m + 1; else hi = m; }
    const int lb = lo;
    lo = 0; hi = N_NODES;
    while (lo < hi) { const int m = (lo + hi) >> 1; if (batch[m] <= g) lo = m + 1; else hi = m; }
    const int cnt = lo - lb;
    const float inv = 1.f / (float)(cnt > 1 ? cnt : 1);
    float acc = bc[c];
    for (int k = 0; k < 64; ++k)
        acc += gsum[g * 64 + k] * inv * wc[k * N_CLS + c];
    out[g * N_CLS + c] = acc;
}

// ---------------------------------------------------------------------------
extern "C" void kernel_launch(void* const* d_in, const int* in_sizes, int n_in,
                              void* d_out, int out_size, void* d_ws, size_t ws_size,
                              hipStream_t stream) {
    const float* x   = (const float*)d_in[0];
    const float* w1a = (const float*)d_in[1];
    const float* b1a = (const float*)d_in[2];
    const float* w1b = (const float*)d_in[3];
    const float* b1b = (const float*)d_in[4];
    const float* w2a = (const float*)d_in[5];
    const float* b2a = (const float*)d_in[6];
    const float* w2b = (const float*)d_in[7];
    const float* b2b = (const float*)d_in[8];
    const float* w3a = (const float*)d_in[9];
    const float* b3a = (const float*)d_in[10];
    const float* w3b = (const float*)d_in[11];
    const float* b3b = (const float*)d_in[12];
    const float* wc  = (const float*)d_in[13];
    const float* bc  = (const float*)d_in[14];
    const int*   ei    = (const int*)d_in[15];
    const int*   batch = (const int*)d_in[16];
    float* out = (float*)d_out;

    // workspace layout (~50.1 MB, 16B-aligned)
    char*   ws     = (char*)d_ws;
    int*    bcnt   = (int*)ws;                      // 391 ints (pad 1568)
    int*    cbase  = (int*)(ws + 1568);             // 391 ints (pad 1568)
    int*    offset = (int*)(ws + 3136);             // N+1 ints (pad 400016)
    int*    csr    = (int*)(ws + 403152);           // E ints = 4,800,000
    int*    bpair  = (int*)(ws + 5203152);          // 391*4096 = 6,406,144
    bf16_t* xbf    = (bf16_t*)(ws + 11609296);      // 12,800,000
    bf16_t* h      = (bf16_t*)(ws + 24409296);      // 12,800,000
    bf16_t* xA     = (bf16_t*)(ws + 37209296);      // 12,800,000
    float*  gsum   = (float*)(ws + 50009296);       // 32,768

    const int e4grid  = (N_EDGES / 4 + 255) / 256;  // 1172
    const int agrid   = (N_NODES * 64) / 256;       // 25000 (exact)
    const int mlpgrid = (N_NODES + 63) / 64;        // 1563

    // x -> bf16
    tobf_kernel<<<(N_NODES * 64) / (256 * 8), 256, 0, stream>>>(x, xbf);

    // CSR build (once, reused 3x)
    hipMemsetAsync(bcnt, 0, 1568, stream);
    binA_kernel<<<e4grid, 256, 0, stream>>>(ei, bcnt, bpair);
    bscan_kernel<<<1, 512, 0, stream>>>(bcnt, cbase, offset);
    sortfill_kernel<<<NBUCK, 256, 0, stream>>>(bpair, bcnt, cbase, offset, csr);

    // layer 1
    agg_kernel<<<agrid, 256, 0, stream>>>(xbf, offset, csr, h);
    mlp_kernel<<<mlpgrid, 256, 0, stream>>>(h, w1a, b1a, w1b, b1b, xA);
    // layer 2
    agg_kernel<<<agrid, 256, 0, stream>>>(xA, offset, csr, h);
    mlp_kernel<<<mlpgrid, 256, 0, stream>>>(h, w2a, b2a, w2b, b2b, xA);
    // layer 3
    agg_kernel<<<agrid, 256, 0, stream>>>(xA, offset, csr, h);
    mlp_kernel<<<mlpgrid, 256, 0, stream>>>(h, w3a, b3a, w3b, b3b, xA);

    // pool + classify
    hipMemsetAsync(gsum, 0, 32768, stream);
    pool_kernel<<<(N_NODES + 511) / 512, 256, 0, stream>>>(xA, batch, gsum);
    cls_kernel<<<N_GRAPH, 64, 0, stream>>>(gsum, batch, wc, bc, out);
}

// Round 8
// 336.383 us; speedup vs baseline: 3.7828x; 1.1297x over previous
//
#include <hip/hip_runtime.h>
#include <hip/hip_bf16.h>

// GIN: 3x [CSR gather-sum + MLP(64->64->64) + relu] + mean-pool(128) + linear(64->10)
// x -> bf16 once; agg gathers bf16 with 8-way ILP, f32 accumulate.
// CSR: 391-bucket binning (packed pairs) + per-bucket counting sort.
// MLP: grid-stride (3 tiles/block) to amortize weight staging; aliased LDS tile.
// Pool: one wave per 16 nodes (high TLP), flush-per-transition atomics.

#define N_NODES 100000
#define N_EDGES 1200000
#define N_GRAPH 128
#define N_CLS   10
#define NBUCK   391        // dst >> 8
#define BCAP    4096       // per-bucket capacity (mean 3070, +18 sigma)
#define BSH     12         // log2(BCAP)

typedef __bf16 bf16_t;
typedef __bf16 bf16x8 __attribute__((ext_vector_type(8)));
typedef float  f32x4  __attribute__((ext_vector_type(4)));

// ---------------- x -> bf16 ----------------
__global__ void tobf_kernel(const float* __restrict__ x, bf16_t* __restrict__ xb) {
    const int i = (blockIdx.x * 256 + threadIdx.x) * 8;
    const f32x4 a = *(const f32x4*)(x + i);
    const f32x4 b = *(const f32x4*)(x + i + 4);
    bf16x8 o;
#pragma unroll
    for (int j = 0; j < 4; ++j) { o[j] = (bf16_t)a[j]; o[4 + j] = (bf16_t)b[j]; }
    *(bf16x8*)(xb + i) = o;
}

// ---------------- CSR build ----------------
__global__ void binA_kernel(const int* __restrict__ ei,
                            int* __restrict__ bcnt,
                            int* __restrict__ bpair) {
    __shared__ int lcnt[NBUCK];
    __shared__ int lbase[NBUCK];
    const int t = threadIdx.x;
    for (int b = t; b < NBUCK; b += 256) lcnt[b] = 0;
    __syncthreads();
    const int e0 = (blockIdx.x * 256 + t) * 4;
    int4 s4, d4; int b[4], r[4];
    const bool valid = e0 < N_EDGES;               // N_EDGES % 4 == 0
    if (valid) {
        s4 = *(const int4*)(ei + e0);
        d4 = *(const int4*)(ei + N_EDGES + e0);
        b[0] = d4.x >> 8; b[1] = d4.y >> 8; b[2] = d4.z >> 8; b[3] = d4.w >> 8;
        r[0] = atomicAdd(&lcnt[b[0]], 1);
        r[1] = atomicAdd(&lcnt[b[1]], 1);
        r[2] = atomicAdd(&lcnt[b[2]], 1);
        r[3] = atomicAdd(&lcnt[b[3]], 1);
    }
    __syncthreads();
    for (int bb = t; bb < NBUCK; bb += 256) {
        const int c = lcnt[bb];
        lbase[bb] = c ? atomicAdd(&bcnt[bb], c) : 0;
    }
    __syncthreads();
    if (valid) {
        const int ss[4] = {s4.x, s4.y, s4.z, s4.w};
        const int dd[4] = {d4.x, d4.y, d4.z, d4.w};
#pragma unroll
        for (int j = 0; j < 4; ++j) {
            const int slot = lbase[b[j]] + r[j];
            if (slot < BCAP)
                bpair[(b[j] << BSH) + slot] = (ss[j] << 8) | (dd[j] & 255);
        }
    }
}

__global__ void bscan_kernel(const int* __restrict__ bcnt, int* __restrict__ cbase,
                             int* __restrict__ offset) {
    __shared__ int l[512];
    const int t = threadIdx.x;
    const int v = (t < NBUCK) ? bcnt[t] : 0;
    l[t] = v;
    __syncthreads();
    for (int d = 1; d < 512; d <<= 1) {
        int u = l[t];
        if (t >= d) u += l[t - d];
        __syncthreads();
        l[t] = u;
        __syncthreads();
    }
    if (t < NBUCK) cbase[t] = l[t] - v;
    if (t == NBUCK - 1) offset[N_NODES] = l[t];
}

__global__ void sortfill_kernel(const int* __restrict__ bpair,
                                const int* __restrict__ bcnt,
                                const int* __restrict__ cbase,
                                int* __restrict__ offset, int* __restrict__ csr) {
    __shared__ int hist[256];
    __shared__ int l[256];
    __shared__ int cursor[256];
    const int b = blockIdx.x;
    const int t = threadIdx.x;
    const int base = b << BSH;
    int cnt = bcnt[b];
    cnt = cnt < BCAP ? cnt : BCAP;

    hist[t] = 0;
    __syncthreads();
    for (int i = t; i < cnt; i += 256)
        atomicAdd(&hist[bpair[base + i] & 255], 1);
    __syncthreads();

    const int v = hist[t];
    l[t] = v;
    __syncthreads();
    for (int d = 1; d < 256; d <<= 1) {
        int u = l[t];
        if (t >= d) u += l[t - d];
        __syncthreads();
        l[t] = u;
        __syncthreads();
    }
    const int gpos = cbase[b] + l[t] - v;           // exclusive
    const int node = (b << 8) + t;
    if (node < N_NODES) offset[node] = gpos;
    cursor[t] = gpos;
    __syncthreads();

    for (int i = t; i < cnt; i += 256) {
        const int p = bpair[base + i];
        const int pos = atomicAdd(&cursor[p & 255], 1);
        csr[pos] = p >> 8;
    }
}

// ---------------------------------------------------------------------------
// hout[n] = bf16( x[n] + sum_{s in N(n)} x[s] ).  One wave per node, 8-way ILP.
// ---------------------------------------------------------------------------
__global__ void agg_kernel(const bf16_t* __restrict__ x,
                           const int* __restrict__ offset,
                           const int* __restrict__ csr,
                           bf16_t* __restrict__ hout) {
    const int node = (blockIdx.x * 256 + threadIdx.x) >> 6;
    const int f = threadIdx.x & 63;
    const int o0 = offset[node];
    const int o1 = offset[node + 1];

    float acc = (float)x[node * 64 + f];
    for (int i = o0; i < o1; i += 64) {
        const int cnt = (o1 - i < 64) ? (o1 - i) : 64;
        int s = 0;
        if (i + f < o1) s = csr[i + f];
        int j = 0;
        for (; j + 8 <= cnt; j += 8) {
            const int s0 = __shfl(s, j + 0), s1 = __shfl(s, j + 1);
            const int s2 = __shfl(s, j + 2), s3 = __shfl(s, j + 3);
            const int s4 = __shfl(s, j + 4), s5 = __shfl(s, j + 5);
            const int s6 = __shfl(s, j + 6), s7 = __shfl(s, j + 7);
            const float v0 = (float)x[s0 * 64 + f], v1 = (float)x[s1 * 64 + f];
            const float v2 = (float)x[s2 * 64 + f], v3 = (float)x[s3 * 64 + f];
            const float v4 = (float)x[s4 * 64 + f], v5 = (float)x[s5 * 64 + f];
            const float v6 = (float)x[s6 * 64 + f], v7 = (float)x[s7 * 64 + f];
            acc += ((v0 + v1) + (v2 + v3)) + ((v4 + v5) + (v6 + v7));
        }
        if (j + 4 <= cnt) {
            const int s0 = __shfl(s, j + 0), s1 = __shfl(s, j + 1);
            const int s2 = __shfl(s, j + 2), s3 = __shfl(s, j + 3);
            const float v0 = (float)x[s0 * 64 + f], v1 = (float)x[s1 * 64 + f];
            const float v2 = (float)x[s2 * 64 + f], v3 = (float)x[s3 * 64 + f];
            acc += (v0 + v1) + (v2 + v3);
            j += 4;
        }
        for (; j < cnt; ++j) {
            const int sj = __shfl(s, j);
            acc += (float)x[sj * 64 + f];
        }
    }
    hout[node * 64 + f] = (bf16_t)acc;
}

// ---------------------------------------------------------------------------
// xout = bf16( relu( relu(hin @ wa + ba) @ wb + bb ) )
// Grid-stride: 521 blocks x 3 tiles. Weights staged once per block into
// fragment-layout LDS. Single per-wave LDS tile reused for h1 and h2
// (per-wave in-order LDS + compiler lgkm waits make aliasing safe).
// ---------------------------------------------------------------------------
__global__ void mlp_kernel(const bf16_t* __restrict__ hin,
                           const float* __restrict__ wa, const float* __restrict__ ba,
                           const float* __restrict__ wb, const float* __restrict__ bb,
                           bf16_t* __restrict__ xout) {
    __shared__ __align__(16) bf16_t wfrag[2][8][64][8];  // [mat][ct*2+ks][lane][j]
    __shared__ __align__(16) bf16_t hs[4][16][72];       // per-wave, reused h1/h2
    __shared__ float biasA[64], biasB[64];

    const int tid  = threadIdx.x;
    const int wv   = tid >> 6;
    const int lane = tid & 63;
    const int l15  = lane & 15;
    const int quad = lane >> 4;

    // ---- stage weights once per block ----
    {
        const int k  = tid >> 2;
        const int n0 = (tid & 3) << 4;
        const int ks = k >> 5, qd = (k >> 3) & 3, jj = k & 7;
        const int fi = ((n0 >> 4) << 1) + ks;
#pragma unroll
        for (int m = 0; m < 2; ++m) {
            const float* w = m ? wb : wa;
            const f32x4 v0 = *(const f32x4*)(w + k * 64 + n0);
            const f32x4 v1 = *(const f32x4*)(w + k * 64 + n0 + 4);
            const f32x4 v2 = *(const f32x4*)(w + k * 64 + n0 + 8);
            const f32x4 v3 = *(const f32x4*)(w + k * 64 + n0 + 12);
#pragma unroll
            for (int l = 0; l < 4; ++l) {
                wfrag[m][fi][qd * 16 + l][jj]      = (bf16_t)v0[l];
                wfrag[m][fi][qd * 16 + 4 + l][jj]  = (bf16_t)v1[l];
                wfrag[m][fi][qd * 16 + 8 + l][jj]  = (bf16_t)v2[l];
                wfrag[m][fi][qd * 16 + 12 + l][jj] = (bf16_t)v3[l];
            }
        }
        if (tid < 64) biasA[tid] = ba[tid];
        else if (tid < 128) biasB[tid - 64] = bb[tid - 64];
    }
    __syncthreads();

    const int ntiles = (N_NODES + 63) / 64;   // 1563
    for (int tile = blockIdx.x; tile < ntiles; tile += gridDim.x) {
        const int rb = tile * 64 + wv * 16;
        const int rowa = rb + l15;
        const int rowc = rowa < N_NODES ? rowa : N_NODES - 1;

        bf16x8 af[2];
#pragma unroll
        for (int ks = 0; ks < 2; ++ks)
            af[ks] = *(const bf16x8*)(hin + rowc * 64 + ks * 32 + quad * 8);

        // GEMM1 -> relu -> hs
#pragma unroll
        for (int ct = 0; ct < 4; ++ct) {
            const bf16x8 b0 = *(const bf16x8*)&wfrag[0][ct * 2 + 0][lane][0];
            const bf16x8 b1 = *(const bf16x8*)&wfrag[0][ct * 2 + 1][lane][0];
            f32x4 acc = {0.f, 0.f, 0.f, 0.f};
            acc = __builtin_amdgcn_mfma_f32_16x16x32_bf16(af[0], b0, acc, 0, 0, 0);
            acc = __builtin_amdgcn_mfma_f32_16x16x32_bf16(af[1], b1, acc, 0, 0, 0);
            const float bv = biasA[ct * 16 + l15];
#pragma unroll
            for (int r = 0; r < 4; ++r) {
                float h = acc[r] + bv;
                h = h > 0.f ? h : 0.f;
                hs[wv][quad * 4 + r][ct * 16 + l15] = (bf16_t)h;
            }
        }

        // h1 -> A layout
        bf16x8 a2[2];
#pragma unroll
        for (int ks = 0; ks < 2; ++ks)
            a2[ks] = *(const bf16x8*)(&hs[wv][l15][ks * 32 + quad * 8]);

        // GEMM2 -> relu -> hs (aliased)
#pragma unroll
        for (int ct = 0; ct < 4; ++ct) {
            const bf16x8 b0 = *(const bf16x8*)&wfrag[1][ct * 2 + 0][lane][0];
            const bf16x8 b1 = *(const bf16x8*)&wfrag[1][ct * 2 + 1][lane][0];
            f32x4 acc = {0.f, 0.f, 0.f, 0.f};
            acc = __builtin_amdgcn_mfma_f32_16x16x32_bf16(a2[0], b0, acc, 0, 0, 0);
            acc = __builtin_amdgcn_mfma_f32_16x16x32_bf16(a2[1], b1, acc, 0, 0, 0);
            const float bv = biasB[ct * 16 + l15];
#pragma unroll
            for (int r = 0; r < 4; ++r) {
                float h = acc[r] + bv;
                h = h > 0.f ? h : 0.f;
                hs[wv][quad * 4 + r][ct * 16 + l15] = (bf16_t)h;
            }
        }

        // coalesced store: 128B contiguous per instruction
        const int colg = (lane & 7) * 8;
#pragma unroll
        for (int sx = 0; sx < 2; ++sx) {
            const int r16 = (lane >> 3) + 8 * sx;
            const int grow = rb + r16;
            const bf16x8 v = *(const bf16x8*)&hs[wv][r16][colg];
            if (grow < N_NODES)
                *(bf16x8*)(xout + grow * 64 + colg) = v;
        }
    }
}

// ---------------------------------------------------------------------------
// Mean-pool numerator: one wave per 16 nodes (6252 waves), flush on transition.
// ---------------------------------------------------------------------------
__global__ void pool_kernel(const bf16_t* __restrict__ x,
                            const int* __restrict__ batch,
                            float* __restrict__ gsum) {
    const int f  = threadIdx.x & 63;
    const int wv = threadIdx.x >> 6;
    const int n0 = (blockIdx.x * 4 + wv) * 16;
    if (n0 >= N_NODES) return;
    const int n1 = (n0 + 16 < N_NODES) ? (n0 + 16) : N_NODES;
    int cur = batch[n0];
    float acc = 0.f;
    for (int n = n0; n < n1; ++n) {
        const int g = batch[n];
        const float v = (float)x[n * 64 + f];
        if (g != cur) {
            unsafeAtomicAdd(gsum + cur * 64 + f, acc);
            acc = 0.f;
            cur = g;
        }
        acc += v;
    }
    unsafeAtomicAdd(gsum + cur * 64 + f, acc);
}

__global__ void cls_kernel(const float* __restrict__ gsum,
                           const int* __restrict__ batch,
                           const float* __restrict__ wc, const float* __restrict__ bc,
                           float* __restrict__ out) {
    const int g = blockIdx.x;
    const int c = threadIdx.x;
    if (c >= N_CLS) return;
    int lo = 0, hi = N_NODES;
    while (lo < hi) { const int m = (lo + hi) >> 1; if (batch[m] < g) lo = m + 1; else hi = m; }
    const int lb = lo;
    lo = 0; hi = N_NODES;
    while (lo < hi) { const int m = (lo + hi) >> 1; if (batch[m] <= g) lo = m + 1; else hi = m; }
    const int cnt = lo - lb;
    const float inv = 1.f / (float)(cnt > 1 ? cnt : 1);
    float acc = bc[c];
    for (int k = 0; k < 64; ++k)
        acc += gsum[g * 64 + k] * inv * wc[k * N_CLS + c];
    out[g * N_CLS + c] = acc;
}

// ---------------------------------------------------------------------------
extern "C" void kernel_launch(void* const* d_in, const int* in_sizes, int n_in,
                              void* d_out, int out_size, void* d_ws, size_t ws_size,
                              hipStream_t stream) {
    const float* x   = (const float*)d_in[0];
    const float* w1a = (const float*)d_in[1];
    const float* b1a = (const float*)d_in[2];
    const float* w1b = (const float*)d_in[3];
    const float* b1b = (const float*)d_in[4];
    const float* w2a = (const float*)d_in[5];
    const float* b2a = (const float*)d_in[6];
    const float* w2b = (const float*)d_in[7];
    const float* b2b = (const float*)d_in[8];
    const float* w3a = (const float*)d_in[9];
    const float* b3a = (const float*)d_in[10];
    const float* w3b = (const float*)d_in[11];
    const float* b3b = (const float*)d_in[12];
    const float* wc  = (const float*)d_in[13];
    const float* bc  = (const float*)d_in[14];
    const int*   ei    = (const int*)d_in[15];
    const int*   batch = (const int*)d_in[16];
    float* out = (float*)d_out;

    // workspace layout (~50.1 MB, 16B-aligned)
    char*   ws     = (char*)d_ws;
    int*    bcnt   = (int*)ws;                      // 391 ints (pad 1568)
    int*    cbase  = (int*)(ws + 1568);             // 391 ints (pad 1568)
    int*    offset = (int*)(ws + 3136);             // N+1 ints (pad 400016)
    int*    csr    = (int*)(ws + 403152);           // E ints = 4,800,000
    int*    bpair  = (int*)(ws + 5203152);          // 391*4096*4 = 6,406,144
    bf16_t* xbf    = (bf16_t*)(ws + 11609296);      // 12,800,000
    bf16_t* h      = (bf16_t*)(ws + 24409296);      // 12,800,000
    bf16_t* xA     = (bf16_t*)(ws + 37209296);      // 12,800,000
    float*  gsum   = (float*)(ws + 50009296);       // 32,768

    const int e4grid  = (N_EDGES / 4 + 255) / 256;  // 1172
    const int agrid   = (N_NODES * 64) / 256;       // 25000 (exact)
    const int mlpgrid = 521;                        // 3 tiles/block (521*3 = 1563)
    const int pgrid   = (N_NODES + 63) / 64;        // 1563

    // x -> bf16
    tobf_kernel<<<(N_NODES * 64) / (256 * 8), 256, 0, stream>>>(x, xbf);

    // CSR build (once, reused 3x)
    hipMemsetAsync(bcnt, 0, 1568, stream);
    binA_kernel<<<e4grid, 256, 0, stream>>>(ei, bcnt, bpair);
    bscan_kernel<<<1, 512, 0, stream>>>(bcnt, cbase, offset);
    sortfill_kernel<<<NBUCK, 256, 0, stream>>>(bpair, bcnt, cbase, offset, csr);

    // layer 1
    agg_kernel<<<agrid, 256, 0, stream>>>(xbf, offset, csr, h);
    mlp_kernel<<<mlpgrid, 256, 0, stream>>>(h, w1a, b1a, w1b, b1b, xA);
    // layer 2
    agg_kernel<<<agrid, 256, 0, stream>>>(xA, offset, csr, h);
    mlp_kernel<<<mlpgrid, 256, 0, stream>>>(h, w2a, b2a, w2b, b2b, xA);
    // layer 3
    agg_kernel<<<agrid, 256, 0, stream>>>(xA, offset, csr, h);
    mlp_kernel<<<mlpgrid, 256, 0, stream>>>(h, w3a, b3a, w3b, b3b, xA);

    // pool + classify
    hipMemsetAsync(gsum, 0, 32768, stream);
    pool_kernel<<<pgrid, 256, 0, stream>>>(xA, batch, gsum);
    cls_kernel<<<N_GRAPH, 64, 0, stream>>>(gsum, batch, wc, bc, out);
}